// Round 9
// baseline (628.186 us; speedup 1.0000x reference)
//
#include <hip/hip_runtime.h>

#define ALPHA 0.2f

typedef short bf16x8 __attribute__((ext_vector_type(8)));
typedef float f32x4  __attribute__((ext_vector_type(4)));

// bf16 helpers (RTN)
__device__ __forceinline__ unsigned short f2bf(float f) {
    unsigned u = __float_as_uint(f);
    u += 0x7FFFu + ((u >> 16) & 1u);
    return (unsigned short)(u >> 16);
}
__device__ __forceinline__ float bflo(unsigned u) {           // low ushort -> f32
    return __uint_as_float(u << 16);
}
__device__ __forceinline__ float bfhi(unsigned u) {           // high ushort -> f32
    return __uint_as_float(u & 0xFFFF0000u);
}

// ---------------------------------------------------------------------------
// f15_wt: tiny W -> WT bf16 transpose (16384 elems). Must precede f15_h.
// ---------------------------------------------------------------------------
__global__ __launch_bounds__(256) void f15_wt(
    const float* __restrict__ W, unsigned short* __restrict__ WT)
{
    int t = blockIdx.x * 256 + threadIdx.x;
    if (t < 2 * 64 * 128) {
        int i = t >> 13;
        int c = (t >> 7) & 63;
        int k = t & 127;
        WT[t] = f2bf(W[i * 8192 + k * 64 + c]);
    }
}

// ---------------------------------------------------------------------------
// f15_h: MFMA GEMM h = x @ W[i] FUSED with edge histogram+rank.
// The 3.3M rank-returning atomics are device-atomic-throughput bound
// (~25 G/s => ~131us); the GEMM (~50us) now hides under that time instead
// of running serially after it.
// Block: 4 waves x 16 rows = 64 rows, one subhead (blockIdx&1).
// Fragment layouts (m89-verified family): A: row=l&15, k=(l>>4)*8+j;
// B: col=l&15, k=(l>>4)*8+j; D: col=l&15, row=(l>>4)*4+reg.
// ---------------------------------------------------------------------------
__global__ __launch_bounds__(256) void f15_h(
    const float* __restrict__ x,             // N x 128 fp32
    const unsigned short* __restrict__ WT,   // [2][64][128] bf16
    const float* __restrict__ a_src, const float* __restrict__ a_dst,
    const int* __restrict__ row, const int* __restrict__ col, int E,
    int* __restrict__ cnt, int* __restrict__ rank,
    unsigned short* __restrict__ Hb,         // N x 128 bf16 (row-major)
    float* __restrict__ s_r, float* __restrict__ s_c, int N)
{
    __shared__ __align__(16) unsigned short hs[4][16][72];  // 9KB; +8 pad/row
    const int t  = threadIdx.x;
    const int wv = t >> 6, l = t & 63;
    const int i  = blockIdx.x & 1;
    const int n0 = (blockIdx.x >> 1) * 64 + wv * 16;
    const int lm = l & 15, lg = l >> 4;

    // fused histogram + rank (grid-stride; each edge exactly once)
    {
        const long total = (long)gridDim.x * 256;
        for (long e = (long)blockIdx.x * 256 + t; e < E; e += total) {
            int r = row[e], c = col[e];
            if ((unsigned)r < (unsigned)N && (unsigned)c < (unsigned)N)
                rank[e] = atomicAdd(cnt + r, 1);
        }
    }

    // A fragments: row n0+lm, convert fp32 -> bf16 in-register
    int arow = n0 + lm; if (arow >= N) arow = N - 1;       // clamped; stores guarded
    const float* xr = x + (size_t)arow * 128 + lg * 8;
    bf16x8 af[4];
    #pragma unroll
    for (int ks = 0; ks < 4; ++ks) {
        float4 u0 = *(const float4*)(xr + ks * 32);
        float4 u1 = *(const float4*)(xr + ks * 32 + 4);
        bf16x8 a;
        a[0] = (short)f2bf(u0.x); a[1] = (short)f2bf(u0.y);
        a[2] = (short)f2bf(u0.z); a[3] = (short)f2bf(u0.w);
        a[4] = (short)f2bf(u1.x); a[5] = (short)f2bf(u1.y);
        a[6] = (short)f2bf(u1.z); a[7] = (short)f2bf(u1.w);
        af[ks] = a;
    }

    // B fragments from WT rows (32KB total, L1/L2-resident)
    const unsigned short* wr = WT + ((size_t)i * 64 + lm) * 128 + lg * 8;
    f32x4 zero = {0.f, 0.f, 0.f, 0.f};
    f32x4 acc[4];
    #pragma unroll
    for (int ct = 0; ct < 4; ++ct) {
        acc[ct] = zero;
        #pragma unroll
        for (int ks = 0; ks < 4; ++ks) {
            bf16x8 bf = *(const bf16x8*)(wr + ct * 16 * 128 + ks * 32);
            acc[ct] = __builtin_amdgcn_mfma_f32_16x16x32_bf16(af[ks], bf, acc[ct], 0, 0, 0);
        }
    }

    // s_r/s_c: row = n0 + lg*4 + reg; reduce over cols (16-lane groups)
    float asv[4], adv[4];
    #pragma unroll
    for (int ct = 0; ct < 4; ++ct) {
        asv[ct] = a_src[i * 64 + ct * 16 + lm];
        adv[ct] = a_dst[i * 64 + ct * 16 + lm];
    }
    #pragma unroll
    for (int reg = 0; reg < 4; ++reg) {
        float vr = 0.f, vc = 0.f;
        #pragma unroll
        for (int ct = 0; ct < 4; ++ct) {
            vr = fmaf(acc[ct][reg], asv[ct], vr);
            vc = fmaf(acc[ct][reg], adv[ct], vc);
        }
        #pragma unroll
        for (int off = 8; off; off >>= 1) {
            vr += __shfl_xor(vr, off);
            vc += __shfl_xor(vc, off);
        }
        int n = n0 + lg * 4 + reg;
        if (lm == 0 && n < N) {
            s_r[(size_t)i * N + n] = vr;
            s_c[(size_t)i * N + n] = vc;
        }
    }

    // H write via per-wave LDS transpose (no barrier: same-wave produce/consume)
    #pragma unroll
    for (int ct = 0; ct < 4; ++ct)
        #pragma unroll
        for (int reg = 0; reg < 4; ++reg)
            hs[wv][lg * 4 + reg][ct * 16 + lm] = f2bf(acc[ct][reg]);
    #pragma unroll
    for (int j = 0; j < 2; ++j) {
        int r = (l >> 3) + j * 8;
        int n = n0 + r;
        if (n < N) {
            int g = (l & 7) * 8;
            *(uint4*)(Hb + (size_t)n * 128 + i * 64 + g) =
                *(const uint4*)&hs[wv][r][g];
        }
    }
}

// ---------------------------------------------------------------------------
// f10_h: LDS-tiled vector GEMM (kept for fp32 fallback paths A/C)
// ---------------------------------------------------------------------------
__global__ __launch_bounds__(256) void f10_h(
    const float* __restrict__ x, const float* __restrict__ W,
    const float* __restrict__ a_src, const float* __restrict__ a_dst,
    const int* __restrict__ row, const int* __restrict__ col, int E,
    int* __restrict__ cnt,
    float* __restrict__ Hf, unsigned short* __restrict__ Hb,
    float* __restrict__ s_r, float* __restrict__ s_c, int N)
{
    __shared__ __align__(16) float ws[128][64];
    __shared__ __align__(16) float xs[128][36];
    const int t  = threadIdx.x;
    const int i  = blockIdx.x & 1;
    const int n0 = (blockIdx.x >> 1) * 32;

    if (cnt) {
        const long total = (long)gridDim.x * 256;
        for (long e = (long)blockIdx.x * 256 + t; e < E; e += total) {
            int r = row[e], c = col[e];
            if ((unsigned)r < (unsigned)N && (unsigned)c < (unsigned)N)
                atomicAdd(cnt + r, 1);
        }
    }
    {
        const float* wp = W + (size_t)i * 8192;
        #pragma unroll
        for (int j = 0; j < 8; ++j) {
            int idx = t + j * 256;
            int k   = idx >> 4;
            int c4  = (idx & 15) * 4;
            *(float4*)&ws[k][c4] = *(const float4*)(wp + k * 64 + c4);
        }
    }
    {
        int r = t >> 3;
        int n = n0 + r;
        #pragma unroll
        for (int j = 0; j < 4; ++j) {
            int k0 = ((t & 7) + j * 8) * 4;
            float4 v = (n < N) ? *(const float4*)(x + (size_t)n * 128 + k0)
                               : make_float4(0.f, 0.f, 0.f, 0.f);
            xs[k0 + 0][r] = v.x; xs[k0 + 1][r] = v.y;
            xs[k0 + 2][r] = v.z; xs[k0 + 3][r] = v.w;
        }
    }
    __syncthreads();

    const int tc = t & 31, tn = t >> 5;
    float acc[4][2] = {};
    #pragma unroll 8
    for (int k = 0; k < 128; ++k) {
        float4 xv = *(const float4*)&xs[k][tn * 4];
        float2 wv = *(const float2*)&ws[k][tc * 2];
        acc[0][0] = fmaf(xv.x, wv.x, acc[0][0]);
        acc[0][1] = fmaf(xv.x, wv.y, acc[0][1]);
        acc[1][0] = fmaf(xv.y, wv.x, acc[1][0]);
        acc[1][1] = fmaf(xv.y, wv.y, acc[1][1]);
        acc[2][0] = fmaf(xv.z, wv.x, acc[2][0]);
        acc[2][1] = fmaf(xv.z, wv.y, acc[2][1]);
        acc[3][0] = fmaf(xv.w, wv.x, acc[3][0]);
        acc[3][1] = fmaf(xv.w, wv.y, acc[3][1]);
    }

    const float2 asv = *(const float2*)(a_src + i * 64 + tc * 2);
    const float2 adv = *(const float2*)(a_dst + i * 64 + tc * 2);
    #pragma unroll
    for (int a = 0; a < 4; ++a) {
        int n = n0 + tn * 4 + a;
        if (n >= N) break;
        float2 hv; hv.x = acc[a][0]; hv.y = acc[a][1];
        if (Hf) *(float2*)(Hf + (size_t)n * 128 + i * 64 + tc * 2) = hv;
        if (Hb) {
            ushort2 hb; hb.x = f2bf(hv.x); hb.y = f2bf(hv.y);
            *(ushort2*)(Hb + (size_t)n * 128 + (i * 32 + tc) * 2) = hb;
        }
        float pr = hv.x * asv.x + hv.y * asv.y;
        float pc = hv.x * adv.x + hv.y * adv.y;
        #pragma unroll
        for (int off = 16; off; off >>= 1) {
            pr += __shfl_xor(pr, off);
            pc += __shfl_xor(pc, off);
        }
        if (tc == 0) {
            s_r[(size_t)i * N + n] = pr;
            s_c[(size_t)i * N + n] = pc;
        }
    }
}

// --------------------------- 3-phase exclusive scan ------------------------
__global__ __launch_bounds__(256) void f8_scan1(
    const int* __restrict__ cnt, int* __restrict__ bsums, int N)
{
    __shared__ int sdat[256];
    int t = threadIdx.x, b = blockIdx.x;
    int s = 0;
    #pragma unroll
    for (int j = 0; j < 4; ++j) {
        int idx = b * 1024 + t * 4 + j;
        if (idx < N) s += cnt[idx];
    }
    sdat[t] = s; __syncthreads();
    for (int o = 1; o < 256; o <<= 1) {
        int add = (t >= o) ? sdat[t - o] : 0;
        __syncthreads();
        sdat[t] += add;
        __syncthreads();
    }
    if (t == 255) bsums[b] = sdat[255];
}
__global__ __launch_bounds__(256) void f8_scan2(
    const int* __restrict__ bsums, int* __restrict__ boffs, int nb)
{
    __shared__ int sdat[256];
    int t = threadIdx.x;
    int v = (t < nb) ? bsums[t] : 0;
    sdat[t] = v; __syncthreads();
    for (int o = 1; o < 256; o <<= 1) {
        int add = (t >= o) ? sdat[t - o] : 0;
        __syncthreads();
        sdat[t] += add;
        __syncthreads();
    }
    if (t < nb) boffs[t] = sdat[t] - v;   // exclusive
}
__global__ __launch_bounds__(256) void f11_scan3(
    int* __restrict__ cnt, const int* __restrict__ boffs,
    int* __restrict__ rp, int N)
{
    __shared__ int sdat[256];
    int t = threadIdx.x, b = blockIdx.x;
    int v[4]; int s = 0;
    #pragma unroll
    for (int j = 0; j < 4; ++j) {
        int idx = b * 1024 + t * 4 + j;
        v[j] = (idx < N) ? cnt[idx] : 0;
        s += v[j];
    }
    sdat[t] = s; __syncthreads();
    for (int o = 1; o < 256; o <<= 1) {
        int add = (t >= o) ? sdat[t - o] : 0;
        __syncthreads();
        sdat[t] += add;
        __syncthreads();
    }
    int excl = boffs[b] + sdat[t] - s;
    #pragma unroll
    for (int j = 0; j < 4; ++j) {
        int idx = b * 1024 + t * 4 + j;
        if (idx < N) {
            rp[idx]  = excl;
            cnt[idx] = excl;              // cursor copy (used by fallback path)
            if (idx == N - 1) rp[N] = excl + v[j];
            excl += v[j];
        }
    }
}

// ---------------------------------------------------------------------------
// f15_scatter: ATOMIC-FREE packed scatter with NONTEMPORAL stores.
// pos = rp[r] + rank[e]. NT store bypasses L2 (random 8B stores were dirtying
// full lines -> 8x write amplification; NT lets the MC write at its granule).
// ---------------------------------------------------------------------------
__global__ __launch_bounds__(256) void f15_scatter(
    const int* __restrict__ row, const int* __restrict__ col, int E,
    const float* __restrict__ s_r, const float* __restrict__ s_c, // [2][N]
    const int* __restrict__ rp, const int* __restrict__ rank,
    unsigned long long* __restrict__ pk, int N)
{
    int e = blockIdx.x * 256 + threadIdx.x;
    if (e >= E) return;
    int r = row[e], c = col[e];
    if ((unsigned)r >= (unsigned)N || (unsigned)c >= (unsigned)N) return;
    int pos = rp[r] + rank[e];
    float e0 = s_r[r] + s_c[c];
    float e1 = s_r[(size_t)N + r] + s_c[(size_t)N + c];
    e0 = (e0 > 0.f) ? e0 : ALPHA * e0;
    e1 = (e1 > 0.f) ? e1 : ALPHA * e1;
    unsigned py = ((unsigned)f2bf(expf(e1)) << 16) | (unsigned)f2bf(expf(e0));
    unsigned long long rec = (unsigned long long)(unsigned)c |
                             ((unsigned long long)py << 32);
    __builtin_nontemporal_store(rec, pk + pos);
}

// legacy scatter (colp only) for the mid path
__global__ __launch_bounds__(256) void f8_scatter(
    const int* __restrict__ row, const int* __restrict__ col, int E,
    int* __restrict__ cur, int* __restrict__ colp, int N)
{
    int e = blockIdx.x * 256 + threadIdx.x;
    if (e >= E) return;
    int r = row[e], c = col[e];
    if ((unsigned)r >= (unsigned)N || (unsigned)c >= (unsigned)N) return;
    int pos = atomicAdd(cur + r, 1);
    colp[pos] = c;
}

// ---------------------------------------------------------------------------
// f12_spmm2: dual-subhead hop-1 SpMM. bf16 H gathers, 8B pk, 8x pipeline,
// inline denominator. Sub0 lanes: fused NodeAdaptiveEncoder -> out[0:64];
// sub1 lanes -> A1b (bf16). (H lives in ws; out written only here.)
// ---------------------------------------------------------------------------
__global__ __launch_bounds__(256) void f12_spmm2(
    const int* __restrict__ rp, const uint2* __restrict__ pk,
    const unsigned* __restrict__ Hb,           // N x 64 uints (bf16 pairs)
    const float* __restrict__ b, const float* __restrict__ fc,
    const float* __restrict__ bfv,
    unsigned short* __restrict__ A1b, float* __restrict__ out, int N)
{
    long gid = (long)blockIdx.x * 256 + threadIdx.x;
    int r = (int)(gid >> 6), d = (int)(gid & 63);
    if (r >= N) return;
    int p0 = rp[r], p1 = rp[r + 1];
    const int sub = d >> 5;
    float a0 = 0.f, a1 = 0.f, den = 0.f;
    int p = p0;
    for (; p + 8 <= p1; p += 8) {
        uint2 m0 = pk[p],     m1 = pk[p + 1], m2 = pk[p + 2], m3 = pk[p + 3];
        uint2 m4 = pk[p + 4], m5 = pk[p + 5], m6 = pk[p + 6], m7 = pk[p + 7];
        unsigned u0 = Hb[(size_t)m0.x * 64 + d];
        unsigned u1 = Hb[(size_t)m1.x * 64 + d];
        unsigned u2 = Hb[(size_t)m2.x * 64 + d];
        unsigned u3 = Hb[(size_t)m3.x * 64 + d];
        unsigned u4 = Hb[(size_t)m4.x * 64 + d];
        unsigned u5 = Hb[(size_t)m5.x * 64 + d];
        unsigned u6 = Hb[(size_t)m6.x * 64 + d];
        unsigned u7 = Hb[(size_t)m7.x * 64 + d];
        float v0 = sub ? bfhi(m0.y) : bflo(m0.y);
        float v1 = sub ? bfhi(m1.y) : bflo(m1.y);
        float v2 = sub ? bfhi(m2.y) : bflo(m2.y);
        float v3 = sub ? bfhi(m3.y) : bflo(m3.y);
        float v4 = sub ? bfhi(m4.y) : bflo(m4.y);
        float v5 = sub ? bfhi(m5.y) : bflo(m5.y);
        float v6 = sub ? bfhi(m6.y) : bflo(m6.y);
        float v7 = sub ? bfhi(m7.y) : bflo(m7.y);
        a0 = fmaf(v0, bflo(u0), a0); a1 = fmaf(v0, bfhi(u0), a1); den += v0;
        a0 = fmaf(v1, bflo(u1), a0); a1 = fmaf(v1, bfhi(u1), a1); den += v1;
        a0 = fmaf(v2, bflo(u2), a0); a1 = fmaf(v2, bfhi(u2), a1); den += v2;
        a0 = fmaf(v3, bflo(u3), a0); a1 = fmaf(v3, bfhi(u3), a1); den += v3;
        a0 = fmaf(v4, bflo(u4), a0); a1 = fmaf(v4, bfhi(u4), a1); den += v4;
        a0 = fmaf(v5, bflo(u5), a0); a1 = fmaf(v5, bfhi(u5), a1); den += v5;
        a0 = fmaf(v6, bflo(u6), a0); a1 = fmaf(v6, bfhi(u6), a1); den += v6;
        a0 = fmaf(v7, bflo(u7), a0); a1 = fmaf(v7, bfhi(u7), a1); den += v7;
    }
    for (; p < p1; ++p) {
        uint2 m = pk[p];
        unsigned u = Hb[(size_t)m.x * 64 + d];
        float v = sub ? bfhi(m.y) : bflo(m.y);
        a0 = fmaf(v, bflo(u), a0); a1 = fmaf(v, bfhi(u), a1); den += v;
    }
    float inv = (p1 > p0) ? 1.f / den : 0.f;
    float r0 = a0 * inv, r1 = a1 * inv;
    if (sub) {
        ushort2 res; res.x = f2bf(r0); res.y = f2bf(r1);
        *(ushort2*)(A1b + (size_t)r * 64 + (d - 32) * 2) = res;
    } else {
        int dcol = 2 * d;
        float vh0 = (r0 != r0) ? 0.f : r0;
        float vh1 = (r1 != r1) ? 0.f : r1;
        float2 bb = *(const float2*)(b + dcol);
        float2 ff = *(const float2*)(fc + dcol);
        vh0 += bb.x; vh1 += bb.y;
        float pp = vh0 * ff.x + vh1 * ff.y;
        #pragma unroll
        for (int off = 16; off; off >>= 1) pp += __shfl_xor(pp, off);
        float g = 1.f / (1.f + expf(-(pp + bfv[0])));
        float q0 = fmaxf(vh0, 0.f) + g * fminf(vh0, 0.f);
        float q1 = fmaxf(vh1, 0.f) + g * fminf(vh1, 0.f);
        q0 = (q0 > 0.f) ? q0 : ALPHA * q0;
        q1 = (q1 > 0.f) ? q1 : ALPHA * q1;
        float2 res; res.x = q0; res.y = q1;
        *(float2*)(out + (size_t)r * 128 + dcol) = res;
    }
}

// ---------------------------------------------------------------------------
// f12_fin2: sub1 hop-2 SpMM (bf16 A1 gathers), fused epilogue -> out[64:128].
// ---------------------------------------------------------------------------
__global__ __launch_bounds__(256) void f12_fin2(
    const int* __restrict__ rp, const uint2* __restrict__ pk,
    const unsigned short* __restrict__ A1b,
    const float* __restrict__ b, const float* __restrict__ fc,
    const float* __restrict__ bfv,
    float* __restrict__ out, int N)
{
    long gid = (long)blockIdx.x * 256 + threadIdx.x;
    int r = (int)(gid >> 6), d = (int)(gid & 63);
    if (r >= N) return;
    int p0 = rp[r], p1 = rp[r + 1];
    float acc = 0.f, den = 0.f;
    int p = p0;
    for (; p + 8 <= p1; p += 8) {
        uint2 m0 = pk[p],     m1 = pk[p + 1], m2 = pk[p + 2], m3 = pk[p + 3];
        uint2 m4 = pk[p + 4], m5 = pk[p + 5], m6 = pk[p + 6], m7 = pk[p + 7];
        float s0 = bflo(A1b[(size_t)m0.x * 64 + d]);
        float s1 = bflo(A1b[(size_t)m1.x * 64 + d]);
        float s2 = bflo(A1b[(size_t)m2.x * 64 + d]);
        float s3 = bflo(A1b[(size_t)m3.x * 64 + d]);
        float s4 = bflo(A1b[(size_t)m4.x * 64 + d]);
        float s5 = bflo(A1b[(size_t)m5.x * 64 + d]);
        float s6 = bflo(A1b[(size_t)m6.x * 64 + d]);
        float s7 = bflo(A1b[(size_t)m7.x * 64 + d]);
        float v0 = bfhi(m0.y), v1 = bfhi(m1.y), v2 = bfhi(m2.y), v3 = bfhi(m3.y);
        float v4 = bfhi(m4.y), v5 = bfhi(m5.y), v6 = bfhi(m6.y), v7 = bfhi(m7.y);
        acc = fmaf(v0, s0, acc); den += v0;
        acc = fmaf(v1, s1, acc); den += v1;
        acc = fmaf(v2, s2, acc); den += v2;
        acc = fmaf(v3, s3, acc); den += v3;
        acc = fmaf(v4, s4, acc); den += v4;
        acc = fmaf(v5, s5, acc); den += v5;
        acc = fmaf(v6, s6, acc); den += v6;
        acc = fmaf(v7, s7, acc); den += v7;
    }
    for (; p < p1; ++p) {
        uint2 m = pk[p];
        float v = bfhi(m.y);
        acc = fmaf(v, bflo(A1b[(size_t)m.x * 64 + d]), acc); den += v;
    }
    float vh = (p1 > p0) ? acc / den : 0.f;
    if (vh != vh) vh = 0.f;
    vh += b[64 + d];
    float pp = vh * fc[64 + d];
    #pragma unroll
    for (int off = 32; off; off >>= 1) pp += __shfl_xor(pp, off);
    float g = 1.f / (1.f + expf(-(pp + bfv[1])));
    float res = fmaxf(vh, 0.f) + g * fminf(vh, 0.f);
    res = (res > 0.f) ? res : ALPHA * res;
    out[(size_t)r * 128 + 64 + d] = res;
}

// ---------------------------------------------------------------------------
// Colp-path kernels (fp32 fallback, race-free structure)
// ---------------------------------------------------------------------------
__global__ __launch_bounds__(256) void f11_spmm2_cp(
    const int* __restrict__ rp, const int* __restrict__ colp,
    const float* __restrict__ s_r, const float* __restrict__ s_c, // [2][N]
    const float* __restrict__ H,
    float* __restrict__ A0, float* __restrict__ A1, int N)
{
    long gid = (long)blockIdx.x * 256 + threadIdx.x;
    int r = (int)(gid >> 6), d = (int)(gid & 63);
    if (r >= N) return;
    int p0 = rp[r], p1 = rp[r + 1];
    const int sub = d >> 5;
    const float* scp = s_c + (size_t)sub * N;
    float sr = s_r[(size_t)sub * N + r];
    const float2* H2 = (const float2*)H;
    float a0 = 0.f, a1 = 0.f, den = 0.f;
    int p = p0;
    for (; p + 4 <= p1; p += 4) {
        int c0 = colp[p], c1 = colp[p + 1], c2 = colp[p + 2], c3 = colp[p + 3];
        float sc0 = scp[c0], sc1 = scp[c1], sc2 = scp[c2], sc3 = scp[c3];
        float2 h0 = H2[(size_t)c0 * 64 + d];
        float2 h1 = H2[(size_t)c1 * 64 + d];
        float2 h2 = H2[(size_t)c2 * 64 + d];
        float2 h3 = H2[(size_t)c3 * 64 + d];
        float e0 = sr + sc0; e0 = (e0 > 0.f) ? e0 : ALPHA * e0; float v0 = expf(e0);
        float e1 = sr + sc1; e1 = (e1 > 0.f) ? e1 : ALPHA * e1; float v1 = expf(e1);
        float e2 = sr + sc2; e2 = (e2 > 0.f) ? e2 : ALPHA * e2; float v2 = expf(e2);
        float e3 = sr + sc3; e3 = (e3 > 0.f) ? e3 : ALPHA * e3; float v3 = expf(e3);
        a0 = fmaf(v0, h0.x, a0); a1 = fmaf(v0, h0.y, a1); den += v0;
        a0 = fmaf(v1, h1.x, a0); a1 = fmaf(v1, h1.y, a1); den += v1;
        a0 = fmaf(v2, h2.x, a0); a1 = fmaf(v2, h2.y, a1); den += v2;
        a0 = fmaf(v3, h3.x, a0); a1 = fmaf(v3, h3.y, a1); den += v3;
    }
    for (; p < p1; ++p) {
        int c = colp[p];
        float e0 = sr + scp[c];
        e0 = (e0 > 0.f) ? e0 : ALPHA * e0;
        float v = expf(e0);
        float2 h = H2[(size_t)c * 64 + d];
        a0 = fmaf(v, h.x, a0); a1 = fmaf(v, h.y, a1); den += v;
    }
    float inv = (p1 > p0) ? 1.f / den : 0.f;
    int dcol = (2 * d) & 63;
    float2 res; res.x = a0 * inv; res.y = a1 * inv;
    float* dst = sub ? A1 : A0;
    *(float2*)(dst + (size_t)r * 64 + dcol) = res;
}

__global__ __launch_bounds__(256) void f9_spmm_fin(
    const int* __restrict__ rp, const int* __restrict__ colp,
    const float* __restrict__ s_r, const float* __restrict__ s_c,
    const float* __restrict__ src, int ss, int soff,
    const float* __restrict__ b, const float* __restrict__ fc,
    const float* __restrict__ bfv,
    float* __restrict__ out, int N, int sub)
{
    long gid = (long)blockIdx.x * 256 + threadIdx.x;
    int r = (int)(gid >> 6), d = (int)(gid & 63);
    if (r >= N) return;
    int p0 = rp[r], p1 = rp[r + 1];
    float sr = s_r[r];
    float acc = 0.f, den = 0.f;
    int p = p0;
    for (; p + 4 <= p1; p += 4) {
        int c0 = colp[p], c1 = colp[p + 1], c2 = colp[p + 2], c3 = colp[p + 3];
        float sc0 = s_c[c0], sc1 = s_c[c1], sc2 = s_c[c2], sc3 = s_c[c3];
        float s0 = src[(size_t)c0 * ss + soff + d];
        float s1 = src[(size_t)c1 * ss + soff + d];
        float s2 = src[(size_t)c2 * ss + soff + d];
        float s3 = src[(size_t)c3 * ss + soff + d];
        float e0 = sr + sc0; e0 = (e0 > 0.f) ? e0 : ALPHA * e0; float v0 = expf(e0);
        float e1 = sr + sc1; e1 = (e1 > 0.f) ? e1 : ALPHA * e1; float v1 = expf(e1);
        float e2 = sr + sc2; e2 = (e2 > 0.f) ? e2 : ALPHA * e2; float v2 = expf(e2);
        float e3 = sr + sc3; e3 = (e3 > 0.f) ? e3 : ALPHA * e3; float v3 = expf(e3);
        acc = fmaf(v0, s0, acc); den += v0;
        acc = fmaf(v1, s1, acc); den += v1;
        acc = fmaf(v2, s2, acc); den += v2;
        acc = fmaf(v3, s3, acc); den += v3;
    }
    for (; p < p1; ++p) {
        int c = colp[p];
        float ev = sr + s_c[c];
        ev = (ev > 0.f) ? ev : ALPHA * ev;
        float v = expf(ev);
        acc = fmaf(v, src[(size_t)c * ss + soff + d], acc);
        den += v;
    }
    float vh = (p1 > p0) ? acc / den : 0.f;
    if (vh != vh) vh = 0.f;
    vh += b[sub * 64 + d];
    float pp = vh * fc[sub * 64 + d];
    #pragma unroll
    for (int off = 32; off; off >>= 1) pp += __shfl_xor(pp, off);
    float g = 1.f / (1.f + expf(-(pp + bfv[sub])));
    float res = fmaxf(vh, 0.f) + g * fminf(vh, 0.f);
    res = (res > 0.f) ? res : ALPHA * res;
    out[(size_t)r * 128 + sub * 64 + d] = res;
}

__global__ __launch_bounds__(256) void f8_fin(
    const float* __restrict__ A,
    const float* __restrict__ b, const float* __restrict__ fc,
    const float* __restrict__ bfv,
    float* __restrict__ out, int N, int sub)
{
    long gid = (long)blockIdx.x * 256 + threadIdx.x;
    int n = (int)(gid >> 6), d = (int)(gid & 63);
    if (n >= N) return;
    float vh = A[(size_t)n * 64 + d];
    if (vh != vh) vh = 0.f;
    vh += b[sub * 64 + d];
    float p = vh * fc[sub * 64 + d];
    #pragma unroll
    for (int off = 32; off; off >>= 1) p += __shfl_xor(p, off);
    float g = 1.f / (1.f + expf(-(p + bfv[sub])));
    float res = fmaxf(vh, 0.f) + g * fminf(vh, 0.f);
    res = (res > 0.f) ? res : ALPHA * res;
    out[(size_t)n * 128 + sub * 64 + d] = res;
}

// ------------------- fallback (R7 atomic path) kernels ---------------------
__global__ __launch_bounds__(256) void f8_edge(
    const int* __restrict__ row, const int* __restrict__ col, int E,
    const float* __restrict__ s_r, const float* __restrict__ s_c,
    float* __restrict__ denom, int* __restrict__ cnt, int N)
{
    int e = blockIdx.x * 256 + threadIdx.x;
    if (e >= E) return;
    int r = row[e], c = col[e];
    if ((unsigned)r >= (unsigned)N || (unsigned)c >= (unsigned)N) return;
    if (cnt) atomicAdd(cnt + r, 1);
    #pragma unroll
    for (int i = 0; i < 2; ++i) {
        float ev = s_r[(size_t)i * N + r] + s_c[(size_t)i * N + c];
        ev = (ev > 0.f) ? ev : ALPHA * ev;
        atomicAdd(denom + (size_t)i * N + r, expf(ev));
    }
}
__global__ __launch_bounds__(256) void f7_spmm(
    const int* __restrict__ row, const int* __restrict__ col, int E,
    const float* __restrict__ s_r, const float* __restrict__ s_c,
    const float* __restrict__ denom,
    const float* __restrict__ out, int hcol,
    float* __restrict__ A, int N)
{
    long gid = (long)blockIdx.x * 256 + threadIdx.x;
    long wv  = gid >> 6;
    int  d   = (int)(gid & 63);
    long e0 = wv * 8, e1 = e0 + 8; if (e1 > E) e1 = E;
    for (long e = e0; e < e1; ++e) {
        int r = row[e], c = col[e];
        if ((unsigned)r >= (unsigned)N || (unsigned)c >= (unsigned)N) continue;
        float ev = s_r[r] + s_c[c];
        ev = (ev > 0.f) ? ev : ALPHA * ev;
        float v = expf(ev) / denom[r];
        atomicAdd(A + (size_t)r * 64 + d, v * out[(size_t)c * 128 + hcol + d]);
    }
}
__global__ __launch_bounds__(256) void f7_copy(
    const float* __restrict__ A, float* __restrict__ out, int cbase, int N)
{
    long gid = (long)blockIdx.x * 256 + threadIdx.x;
    long n = gid >> 6; int d = (int)(gid & 63);
    if (n >= N) return;
    out[(size_t)n * 128 + cbase + d] = A[(size_t)n * 64 + d];
}

extern "C" void kernel_launch(void* const* d_in, const int* in_sizes, int n_in,
                              void* d_out, int out_size, void* d_ws, size_t ws_size,
                              hipStream_t stream) {
    const float* x     = (const float*)d_in[0];
    const int*   ei    = (const int*)d_in[1];
    const float* W     = (const float*)d_in[2];
    const float* b     = (const float*)d_in[3];
    const float* fc    = (const float*)d_in[4];
    const float* bfv   = (const float*)d_in[5];
    const float* a_src = (const float*)d_in[6];
    const float* a_dst = (const float*)d_in[7];
    float* out = (float*)d_out;

    const int N = in_sizes[0] / 128;
    const int E = in_sizes[1] / 2;
    const int* row = ei;
    const int* col = ei + E;
    (void)n_in; (void)out_size;

    // --- Path P5 (MFMA fused-hist + bf16 + rank, ~81 MB):
    //   Hb[N*128 u16] | A1b[N*64 u16] | WT[16384 u16] | rank[E int] |
    //   pk[E*8B] | s_r | s_c | rp | cnt | scan tmp
    unsigned short* Hb   = (unsigned short*)d_ws;
    unsigned short* A1b  = Hb + (size_t)N * 128;
    unsigned short* WT   = A1b + (size_t)N * 64;
    int*            rank = (int*)(WT + 16384);
    uint2*          pk   = (uint2*)(rank + E);
    float*          s_rP = (float*)(pk + E);
    float*          s_cP = s_rP + 2 * (size_t)N;
    int*            rpP  = (int*)(s_cP + 2 * (size_t)N);
    int*            cntP = rpP + (N + 1);
    int*            bsumP = cntP + N;
    int*            boffP = bsumP + 256;
    size_t          needP = (size_t)((char*)(boffP + 256) - (char*)d_ws);

    // --- Path A (colp fp32, ~67 MB): A0 | A1 | colp | s | rp | cnt | scan
    float* A0a   = (float*)d_ws;
    float* A1a   = A0a + (size_t)N * 64;
    int*   colpA = (int*)(A1a + (size_t)N * 64);
    float* s_rA  = (float*)(colpA + E);
    float* s_cA  = s_rA + 2 * (size_t)N;
    int*   rpA   = (int*)(s_cA + 2 * (size_t)N);
    int*   cntA  = rpA + (N + 1);
    int*   bsumA = cntA + N;
    int*   boffA = bsumA + 256;
    size_t needA = (size_t)((char*)(boffA + 256) - (char*)d_ws);

    const int g10 = 2 * ((N + 31) / 32);     // f10_h grid
    const int g15 = 2 * ((N + 63) / 64);     // f15_h grid (64 rows/block)
    const int eb  = (E + 255) / 256;
    const int rb  = (int)(((long)N * 64 + 255) / 256);
    const int nb  = (N + 1023) / 1024;

    if (ws_size >= needP) {
        // ========= Path P5 (MFMA GEMM fused with histogram+rank) ==========
        hipMemsetAsync(cntP, 0, (size_t)N * sizeof(int), stream);
        f15_wt<<<64, 256, 0, stream>>>(W, WT);
        f15_h<<<g15, 256, 0, stream>>>(x, WT, a_src, a_dst, row, col, E,
                                       cntP, rank, Hb, s_rP, s_cP, N);
        f8_scan1<<<nb, 256, 0, stream>>>(cntP, bsumP, N);
        f8_scan2<<<1, 256, 0, stream>>>(bsumP, boffP, nb);
        f11_scan3<<<nb, 256, 0, stream>>>(cntP, boffP, rpP, N);
        f15_scatter<<<eb, 256, 0, stream>>>(row, col, E, s_rP, s_cP, rpP,
                                            rank, (unsigned long long*)pk, N);
        f12_spmm2<<<rb, 256, 0, stream>>>(rpP, pk, (const unsigned*)Hb,
                                          b, fc, bfv, A1b, out, N);
        f12_fin2<<<rb, 256, 0, stream>>>(rpP, pk, A1b, b, fc, bfv, out, N);
    } else if (ws_size >= needA) {
        // ======================= Path A (colp CSR) ========================
        hipMemsetAsync(cntA, 0, (size_t)N * sizeof(int), stream);
        f10_h<<<g10, 256, 0, stream>>>(x, W, a_src, a_dst, row, col, E, cntA,
                                       out, nullptr, s_rA, s_cA, N);
        f8_scan1<<<nb, 256, 0, stream>>>(cntA, bsumA, N);
        f8_scan2<<<1, 256, 0, stream>>>(bsumA, boffA, nb);
        f11_scan3<<<nb, 256, 0, stream>>>(cntA, boffA, rpA, N);
        f8_scatter<<<eb, 256, 0, stream>>>(row, col, E, cntA, colpA, N);
        f11_spmm2_cp<<<rb, 256, 0, stream>>>(rpA, colpA, s_rA, s_cA, out,
                                             A0a, A1a, N);
        f8_fin<<<rb, 256, 0, stream>>>(A0a, b, fc, bfv, out, N, 0);
        f9_spmm_fin<<<rb, 256, 0, stream>>>(rpA, colpA, s_rA + N, s_cA + N,
                                            A1a, 64, 0, b, fc, bfv, out, N, 1);
    } else {
        // ================= Path C (proven R7 atomic path) =================
        float* A     = (float*)d_ws;
        float* s_r   = A + (size_t)N * 64;
        float* s_c   = s_r + 2 * (size_t)N;
        float* denom = s_c + 2 * (size_t)N;
        const size_t planeB = (size_t)N * 64 * sizeof(float);
        const int sb = (int)(((((long)E + 7) / 8) * 64 + 255) / 256);
        hipMemsetAsync(denom, 0, 2 * (size_t)N * sizeof(float), stream);
        f10_h<<<g10, 256, 0, stream>>>(x, W, a_src, a_dst, row, col, E, nullptr,
                                       out, nullptr, s_r, s_c, N);
        f8_edge<<<eb, 256, 0, stream>>>(row, col, E, s_r, s_c, denom, nullptr, N);
        const float* s_r1 = s_r + N; const float* s_c1 = s_c + N; const float* den1 = denom + N;
        hipMemsetAsync(A, 0, planeB, stream);
        f7_spmm<<<sb, 256, 0, stream>>>(row, col, E, s_r, s_c, denom, out, 0, A, N);
        f8_fin<<<rb, 256, 0, stream>>>(A, b, fc, bfv, out, N, 0);
        hipMemsetAsync(A, 0, planeB, stream);
        f7_spmm<<<sb, 256, 0, stream>>>(row, col, E, s_r1, s_c1, den1, out, 64, A, N);
        f7_copy<<<rb, 256, 0, stream>>>(A, out, 64, N);
        hipMemsetAsync(A, 0, planeB, stream);
        f7_spmm<<<sb, 256, 0, stream>>>(row, col, E, s_r1, s_c1, den1, out, 64, A, N);
        f8_fin<<<rb, 256, 0, stream>>>(A, b, fc, bfv, out, N, 1);
    }
}

// Round 10
// 582.510 us; speedup vs baseline: 1.0784x; 1.0784x over previous
//
#include <hip/hip_runtime.h>

#define ALPHA 0.2f
#define CSTRIDE 16   // one cnt counter per 64B line (atomic line-conflict fix)

typedef short bf16x8 __attribute__((ext_vector_type(8)));
typedef float f32x4  __attribute__((ext_vector_type(4)));

// bf16 helpers (RTN)
__device__ __forceinline__ unsigned short f2bf(float f) {
    unsigned u = __float_as_uint(f);
    u += 0x7FFFu + ((u >> 16) & 1u);
    return (unsigned short)(u >> 16);
}
__device__ __forceinline__ float bflo(unsigned u) {           // low ushort -> f32
    return __uint_as_float(u << 16);
}
__device__ __forceinline__ float bfhi(unsigned u) {           // high ushort -> f32
    return __uint_as_float(u & 0xFFFF0000u);
}

// ---------------------------------------------------------------------------
// f14_prep: edge histogram (STRIDED cnt: 1 counter/64B line -> line-level
// atomic parallelism) + per-edge rank + W -> WT bf16 transpose.
// ---------------------------------------------------------------------------
__global__ __launch_bounds__(256) void f14_prep(
    const float* __restrict__ W,
    const int* __restrict__ row, const int* __restrict__ col, int E,
    int* __restrict__ cnt, int* __restrict__ rank,
    unsigned short* __restrict__ WT, int N)
{
    long gid = (long)blockIdx.x * 256 + threadIdx.x;
    const long total = (long)gridDim.x * 256;
    if (gid < E) {
        int r = row[gid], c = col[gid];
        if ((unsigned)r < (unsigned)N && (unsigned)c < (unsigned)N)
            rank[gid] = atomicAdd(cnt + (size_t)r * CSTRIDE, 1);
    }
    // WT[i][c][k] = W[i][k][c]  (16384 elems, tiny)
    for (long t = gid; t < 2 * 64 * 128; t += total) {
        int i = (int)(t >> 13);
        int c = (int)((t >> 7) & 63);
        int k = (int)(t & 127);
        WT[t] = f2bf(W[i * 8192 + k * 64 + c]);
    }
}

// ---------------------------------------------------------------------------
// f14_h: MFMA GEMM h = x @ W[i] (x -> bf16 in-register), fused s_r/s_c dots,
// LDS-transposed vectorized Hb write. (R8-proven.)
// Fragment layouts (m89-verified family): A: row=l&15, k=(l>>4)*8+j;
// B: col=l&15, k=(l>>4)*8+j; D: col=l&15, row=(l>>4)*4+reg.
// ---------------------------------------------------------------------------
__global__ __launch_bounds__(256) void f14_h(
    const float* __restrict__ x,             // N x 128 fp32
    const unsigned short* __restrict__ WT,   // [2][64][128] bf16
    const float* __restrict__ a_src, const float* __restrict__ a_dst,
    unsigned short* __restrict__ Hb,         // N x 128 bf16 (row-major)
    float* __restrict__ s_r, float* __restrict__ s_c, int N)
{
    __shared__ __align__(16) unsigned short hs[4][16][72];  // 9KB; +8 pad/row
    const int t  = threadIdx.x;
    const int wv = t >> 6, l = t & 63;
    const int i  = blockIdx.x & 1;
    const int n0 = (blockIdx.x >> 1) * 64 + wv * 16;
    const int lm = l & 15, lg = l >> 4;

    int arow = n0 + lm; if (arow >= N) arow = N - 1;       // clamped; stores guarded
    const float* xr = x + (size_t)arow * 128 + lg * 8;
    bf16x8 af[4];
    #pragma unroll
    for (int ks = 0; ks < 4; ++ks) {
        float4 u0 = *(const float4*)(xr + ks * 32);
        float4 u1 = *(const float4*)(xr + ks * 32 + 4);
        bf16x8 a;
        a[0] = (short)f2bf(u0.x); a[1] = (short)f2bf(u0.y);
        a[2] = (short)f2bf(u0.z); a[3] = (short)f2bf(u0.w);
        a[4] = (short)f2bf(u1.x); a[5] = (short)f2bf(u1.y);
        a[6] = (short)f2bf(u1.z); a[7] = (short)f2bf(u1.w);
        af[ks] = a;
    }

    const unsigned short* wr = WT + ((size_t)i * 64 + lm) * 128 + lg * 8;
    f32x4 zero = {0.f, 0.f, 0.f, 0.f};
    f32x4 acc[4];
    #pragma unroll
    for (int ct = 0; ct < 4; ++ct) {
        acc[ct] = zero;
        #pragma unroll
        for (int ks = 0; ks < 4; ++ks) {
            bf16x8 bf = *(const bf16x8*)(wr + ct * 16 * 128 + ks * 32);
            acc[ct] = __builtin_amdgcn_mfma_f32_16x16x32_bf16(af[ks], bf, acc[ct], 0, 0, 0);
        }
    }

    float asv[4], adv[4];
    #pragma unroll
    for (int ct = 0; ct < 4; ++ct) {
        asv[ct] = a_src[i * 64 + ct * 16 + lm];
        adv[ct] = a_dst[i * 64 + ct * 16 + lm];
    }
    #pragma unroll
    for (int reg = 0; reg < 4; ++reg) {
        float vr = 0.f, vc = 0.f;
        #pragma unroll
        for (int ct = 0; ct < 4; ++ct) {
            vr = fmaf(acc[ct][reg], asv[ct], vr);
            vc = fmaf(acc[ct][reg], adv[ct], vc);
        }
        #pragma unroll
        for (int off = 8; off; off >>= 1) {
            vr += __shfl_xor(vr, off);
            vc += __shfl_xor(vc, off);
        }
        int n = n0 + lg * 4 + reg;
        if (lm == 0 && n < N) {
            s_r[(size_t)i * N + n] = vr;
            s_c[(size_t)i * N + n] = vc;
        }
    }

    // H write via per-wave LDS transpose (no barrier: same-wave produce/consume)
    #pragma unroll
    for (int ct = 0; ct < 4; ++ct)
        #pragma unroll
        for (int reg = 0; reg < 4; ++reg)
            hs[wv][lg * 4 + reg][ct * 16 + lm] = f2bf(acc[ct][reg]);
    #pragma unroll
    for (int j = 0; j < 2; ++j) {
        int r = (l >> 3) + j * 8;
        int n = n0 + r;
        if (n < N) {
            int g = (l & 7) * 8;
            *(uint4*)(Hb + (size_t)n * 128 + i * 64 + g) =
                *(const uint4*)&hs[wv][r][g];
        }
    }
}

// ---------------------------------------------------------------------------
// f10_h: LDS-tiled vector GEMM (kept for fp32 fallback paths A/C)
// ---------------------------------------------------------------------------
__global__ __launch_bounds__(256) void f10_h(
    const float* __restrict__ x, const float* __restrict__ W,
    const float* __restrict__ a_src, const float* __restrict__ a_dst,
    const int* __restrict__ row, const int* __restrict__ col, int E,
    int* __restrict__ cnt,
    float* __restrict__ Hf, unsigned short* __restrict__ Hb,
    float* __restrict__ s_r, float* __restrict__ s_c, int N)
{
    __shared__ __align__(16) float ws[128][64];
    __shared__ __align__(16) float xs[128][36];
    const int t  = threadIdx.x;
    const int i  = blockIdx.x & 1;
    const int n0 = (blockIdx.x >> 1) * 32;

    if (cnt) {
        const long total = (long)gridDim.x * 256;
        for (long e = (long)blockIdx.x * 256 + t; e < E; e += total) {
            int r = row[e], c = col[e];
            if ((unsigned)r < (unsigned)N && (unsigned)c < (unsigned)N)
                atomicAdd(cnt + r, 1);
        }
    }
    {
        const float* wp = W + (size_t)i * 8192;
        #pragma unroll
        for (int j = 0; j < 8; ++j) {
            int idx = t + j * 256;
            int k   = idx >> 4;
            int c4  = (idx & 15) * 4;
            *(float4*)&ws[k][c4] = *(const float4*)(wp + k * 64 + c4);
        }
    }
    {
        int r = t >> 3;
        int n = n0 + r;
        #pragma unroll
        for (int j = 0; j < 4; ++j) {
            int k0 = ((t & 7) + j * 8) * 4;
            float4 v = (n < N) ? *(const float4*)(x + (size_t)n * 128 + k0)
                               : make_float4(0.f, 0.f, 0.f, 0.f);
            xs[k0 + 0][r] = v.x; xs[k0 + 1][r] = v.y;
            xs[k0 + 2][r] = v.z; xs[k0 + 3][r] = v.w;
        }
    }
    __syncthreads();

    const int tc = t & 31, tn = t >> 5;
    float acc[4][2] = {};
    #pragma unroll 8
    for (int k = 0; k < 128; ++k) {
        float4 xv = *(const float4*)&xs[k][tn * 4];
        float2 wv = *(const float2*)&ws[k][tc * 2];
        acc[0][0] = fmaf(xv.x, wv.x, acc[0][0]);
        acc[0][1] = fmaf(xv.x, wv.y, acc[0][1]);
        acc[1][0] = fmaf(xv.y, wv.x, acc[1][0]);
        acc[1][1] = fmaf(xv.y, wv.y, acc[1][1]);
        acc[2][0] = fmaf(xv.z, wv.x, acc[2][0]);
        acc[2][1] = fmaf(xv.z, wv.y, acc[2][1]);
        acc[3][0] = fmaf(xv.w, wv.x, acc[3][0]);
        acc[3][1] = fmaf(xv.w, wv.y, acc[3][1]);
    }

    const float2 asv = *(const float2*)(a_src + i * 64 + tc * 2);
    const float2 adv = *(const float2*)(a_dst + i * 64 + tc * 2);
    #pragma unroll
    for (int a = 0; a < 4; ++a) {
        int n = n0 + tn * 4 + a;
        if (n >= N) break;
        float2 hv; hv.x = acc[a][0]; hv.y = acc[a][1];
        if (Hf) *(float2*)(Hf + (size_t)n * 128 + i * 64 + tc * 2) = hv;
        if (Hb) {
            ushort2 hb; hb.x = f2bf(hv.x); hb.y = f2bf(hv.y);
            *(ushort2*)(Hb + (size_t)n * 128 + (i * 32 + tc) * 2) = hb;
        }
        float pr = hv.x * asv.x + hv.y * asv.y;
        float pc = hv.x * adv.x + hv.y * adv.y;
        #pragma unroll
        for (int off = 16; off; off >>= 1) {
            pr += __shfl_xor(pr, off);
            pc += __shfl_xor(pc, off);
        }
        if (tc == 0) {
            s_r[(size_t)i * N + n] = pr;
            s_c[(size_t)i * N + n] = pc;
        }
    }
}

// --------------- 3-phase exclusive scan (stride-aware cnt) -----------------
__global__ __launch_bounds__(256) void f16_scan1(
    const int* __restrict__ cnt, int* __restrict__ bsums, int N, int cs)
{
    __shared__ int sdat[256];
    int t = threadIdx.x, b = blockIdx.x;
    int s = 0;
    #pragma unroll
    for (int j = 0; j < 4; ++j) {
        int idx = b * 1024 + t * 4 + j;
        if (idx < N) s += cnt[(size_t)idx * cs];
    }
    sdat[t] = s; __syncthreads();
    for (int o = 1; o < 256; o <<= 1) {
        int add = (t >= o) ? sdat[t - o] : 0;
        __syncthreads();
        sdat[t] += add;
        __syncthreads();
    }
    if (t == 255) bsums[b] = sdat[255];
}
__global__ __launch_bounds__(256) void f8_scan2(
    const int* __restrict__ bsums, int* __restrict__ boffs, int nb)
{
    __shared__ int sdat[256];
    int t = threadIdx.x;
    int v = (t < nb) ? bsums[t] : 0;
    sdat[t] = v; __syncthreads();
    for (int o = 1; o < 256; o <<= 1) {
        int add = (t >= o) ? sdat[t - o] : 0;
        __syncthreads();
        sdat[t] += add;
        __syncthreads();
    }
    if (t < nb) boffs[t] = sdat[t] - v;   // exclusive
}
__global__ __launch_bounds__(256) void f16_scan3(
    int* __restrict__ cnt, const int* __restrict__ boffs,
    int* __restrict__ rp, int N, int cs)
{
    __shared__ int sdat[256];
    int t = threadIdx.x, b = blockIdx.x;
    int v[4]; int s = 0;
    #pragma unroll
    for (int j = 0; j < 4; ++j) {
        int idx = b * 1024 + t * 4 + j;
        v[j] = (idx < N) ? cnt[(size_t)idx * cs] : 0;
        s += v[j];
    }
    sdat[t] = s; __syncthreads();
    for (int o = 1; o < 256; o <<= 1) {
        int add = (t >= o) ? sdat[t - o] : 0;
        __syncthreads();
        sdat[t] += add;
        __syncthreads();
    }
    int excl = boffs[b] + sdat[t] - s;
    #pragma unroll
    for (int j = 0; j < 4; ++j) {
        int idx = b * 1024 + t * 4 + j;
        if (idx < N) {
            rp[idx] = excl;
            if (cs == 1) cnt[idx] = excl;     // cursor copy (fallback path only)
            if (idx == N - 1) rp[N] = excl + v[j];
            excl += v[j];
        }
    }
}

// ---------------------------------------------------------------------------
// f14_scatter: atomic-free packed scatter (PLAIN stores — NT regressed in R9:
// same-row edges land contiguously in pk, so L2 WAS coalescing them).
// ---------------------------------------------------------------------------
__global__ __launch_bounds__(256) void f14_scatter(
    const int* __restrict__ row, const int* __restrict__ col, int E,
    const float* __restrict__ s_r, const float* __restrict__ s_c, // [2][N]
    const int* __restrict__ rp, const int* __restrict__ rank,
    uint2* __restrict__ pk, int N)
{
    int e = blockIdx.x * 256 + threadIdx.x;
    if (e >= E) return;
    int r = row[e], c = col[e];
    if ((unsigned)r >= (unsigned)N || (unsigned)c >= (unsigned)N) return;
    int pos = rp[r] + rank[e];
    float e0 = s_r[r] + s_c[c];
    float e1 = s_r[(size_t)N + r] + s_c[(size_t)N + c];
    e0 = (e0 > 0.f) ? e0 : ALPHA * e0;
    e1 = (e1 > 0.f) ? e1 : ALPHA * e1;
    unsigned py = ((unsigned)f2bf(expf(e1)) << 16) | (unsigned)f2bf(expf(e0));
    uint2 m; m.x = (unsigned)c; m.y = py;
    pk[pos] = m;
}

// legacy scatter (colp only) for the mid path
__global__ __launch_bounds__(256) void f8_scatter(
    const int* __restrict__ row, const int* __restrict__ col, int E,
    int* __restrict__ cur, int* __restrict__ colp, int N)
{
    int e = blockIdx.x * 256 + threadIdx.x;
    if (e >= E) return;
    int r = row[e], c = col[e];
    if ((unsigned)r >= (unsigned)N || (unsigned)c >= (unsigned)N) return;
    int pos = atomicAdd(cur + r, 1);
    colp[pos] = c;
}

// ---------------------------------------------------------------------------
// f12_spmm2: dual-subhead hop-1 SpMM. bf16 H gathers, 8B pk, 8x pipeline,
// inline denominator. Sub0 lanes: fused NodeAdaptiveEncoder -> out[0:64];
// sub1 lanes -> A1b (bf16).
// ---------------------------------------------------------------------------
__global__ __launch_bounds__(256) void f12_spmm2(
    const int* __restrict__ rp, const uint2* __restrict__ pk,
    const unsigned* __restrict__ Hb,           // N x 64 uints (bf16 pairs)
    const float* __restrict__ b, const float* __restrict__ fc,
    const float* __restrict__ bfv,
    unsigned short* __restrict__ A1b, float* __restrict__ out, int N)
{
    long gid = (long)blockIdx.x * 256 + threadIdx.x;
    int r = (int)(gid >> 6), d = (int)(gid & 63);
    if (r >= N) return;
    int p0 = rp[r], p1 = rp[r + 1];
    const int sub = d >> 5;
    float a0 = 0.f, a1 = 0.f, den = 0.f;
    int p = p0;
    for (; p + 8 <= p1; p += 8) {
        uint2 m0 = pk[p],     m1 = pk[p + 1], m2 = pk[p + 2], m3 = pk[p + 3];
        uint2 m4 = pk[p + 4], m5 = pk[p + 5], m6 = pk[p + 6], m7 = pk[p + 7];
        unsigned u0 = Hb[(size_t)m0.x * 64 + d];
        unsigned u1 = Hb[(size_t)m1.x * 64 + d];
        unsigned u2 = Hb[(size_t)m2.x * 64 + d];
        unsigned u3 = Hb[(size_t)m3.x * 64 + d];
        unsigned u4 = Hb[(size_t)m4.x * 64 + d];
        unsigned u5 = Hb[(size_t)m5.x * 64 + d];
        unsigned u6 = Hb[(size_t)m6.x * 64 + d];
        unsigned u7 = Hb[(size_t)m7.x * 64 + d];
        float v0 = sub ? bfhi(m0.y) : bflo(m0.y);
        float v1 = sub ? bfhi(m1.y) : bflo(m1.y);
        float v2 = sub ? bfhi(m2.y) : bflo(m2.y);
        float v3 = sub ? bfhi(m3.y) : bflo(m3.y);
        float v4 = sub ? bfhi(m4.y) : bflo(m4.y);
        float v5 = sub ? bfhi(m5.y) : bflo(m5.y);
        float v6 = sub ? bfhi(m6.y) : bflo(m6.y);
        float v7 = sub ? bfhi(m7.y) : bflo(m7.y);
        a0 = fmaf(v0, bflo(u0), a0); a1 = fmaf(v0, bfhi(u0), a1); den += v0;
        a0 = fmaf(v1, bflo(u1), a0); a1 = fmaf(v1, bfhi(u1), a1); den += v1;
        a0 = fmaf(v2, bflo(u2), a0); a1 = fmaf(v2, bfhi(u2), a1); den += v2;
        a0 = fmaf(v3, bflo(u3), a0); a1 = fmaf(v3, bfhi(u3), a1); den += v3;
        a0 = fmaf(v4, bflo(u4), a0); a1 = fmaf(v4, bfhi(u4), a1); den += v4;
        a0 = fmaf(v5, bflo(u5), a0); a1 = fmaf(v5, bfhi(u5), a1); den += v5;
        a0 = fmaf(v6, bflo(u6), a0); a1 = fmaf(v6, bfhi(u6), a1); den += v6;
        a0 = fmaf(v7, bflo(u7), a0); a1 = fmaf(v7, bfhi(u7), a1); den += v7;
    }
    for (; p < p1; ++p) {
        uint2 m = pk[p];
        unsigned u = Hb[(size_t)m.x * 64 + d];
        float v = sub ? bfhi(m.y) : bflo(m.y);
        a0 = fmaf(v, bflo(u), a0); a1 = fmaf(v, bfhi(u), a1); den += v;
    }
    float inv = (p1 > p0) ? 1.f / den : 0.f;
    float r0 = a0 * inv, r1 = a1 * inv;
    if (sub) {
        ushort2 res; res.x = f2bf(r0); res.y = f2bf(r1);
        *(ushort2*)(A1b + (size_t)r * 64 + (d - 32) * 2) = res;
    } else {
        int dcol = 2 * d;
        float vh0 = (r0 != r0) ? 0.f : r0;
        float vh1 = (r1 != r1) ? 0.f : r1;
        float2 bb = *(const float2*)(b + dcol);
        float2 ff = *(const float2*)(fc + dcol);
        vh0 += bb.x; vh1 += bb.y;
        float pp = vh0 * ff.x + vh1 * ff.y;
        #pragma unroll
        for (int off = 16; off; off >>= 1) pp += __shfl_xor(pp, off);
        float g = 1.f / (1.f + expf(-(pp + bfv[0])));
        float q0 = fmaxf(vh0, 0.f) + g * fminf(vh0, 0.f);
        float q1 = fmaxf(vh1, 0.f) + g * fminf(vh1, 0.f);
        q0 = (q0 > 0.f) ? q0 : ALPHA * q0;
        q1 = (q1 > 0.f) ? q1 : ALPHA * q1;
        float2 res; res.x = q0; res.y = q1;
        *(float2*)(out + (size_t)r * 128 + dcol) = res;
    }
}

// ---------------------------------------------------------------------------
// f16_fin2: sub1 hop-2 SpMM, DUAL-EDGE wave layout: lanes 0-31 process even
// edges, lanes 32-63 odd edges; each lane loads a 4B bf16-pair (2 cols) from
// A1 (was 2B/lane). Half-combine via shfl_xor(32), fused epilogue.
// ---------------------------------------------------------------------------
__global__ __launch_bounds__(256) void f16_fin2(
    const int* __restrict__ rp, const uint2* __restrict__ pk,
    const unsigned* __restrict__ A1u,          // N x 32 uints (bf16 pairs)
    const float* __restrict__ b, const float* __restrict__ fc,
    const float* __restrict__ bfv,
    float* __restrict__ out, int N)
{
    long gid = (long)blockIdx.x * 256 + threadIdx.x;
    int r = (int)(gid >> 6), l = (int)(gid & 63);
    if (r >= N) return;
    const int half = l >> 5, lh = l & 31;
    int p0 = rp[r], p1 = rp[r + 1];
    float a0 = 0.f, a1 = 0.f, den = 0.f;
    int p = p0;
    for (; p + 8 <= p1; p += 8) {      // 8 edges/iter, 4 per half
        uint2 m0 = pk[p + half],     m1 = pk[p + 2 + half];
        uint2 m2 = pk[p + 4 + half], m3 = pk[p + 6 + half];
        unsigned u0 = A1u[(size_t)m0.x * 32 + lh];
        unsigned u1 = A1u[(size_t)m1.x * 32 + lh];
        unsigned u2 = A1u[(size_t)m2.x * 32 + lh];
        unsigned u3 = A1u[(size_t)m3.x * 32 + lh];
        float v0 = bfhi(m0.y), v1 = bfhi(m1.y);
        float v2 = bfhi(m2.y), v3 = bfhi(m3.y);
        a0 = fmaf(v0, bflo(u0), a0); a1 = fmaf(v0, bfhi(u0), a1); den += v0;
        a0 = fmaf(v1, bflo(u1), a0); a1 = fmaf(v1, bfhi(u1), a1); den += v1;
        a0 = fmaf(v2, bflo(u2), a0); a1 = fmaf(v2, bfhi(u2), a1); den += v2;
        a0 = fmaf(v3, bflo(u3), a0); a1 = fmaf(v3, bfhi(u3), a1); den += v3;
    }
    for (; p + 2 <= p1; p += 2) {
        uint2 m = pk[p + half];
        unsigned u = A1u[(size_t)m.x * 32 + lh];
        float v = bfhi(m.y);
        a0 = fmaf(v, bflo(u), a0); a1 = fmaf(v, bfhi(u), a1); den += v;
    }
    if (p < p1 && half == 0) {          // odd remainder: half 0 only
        uint2 m = pk[p];
        unsigned u = A1u[(size_t)m.x * 32 + lh];
        float v = bfhi(m.y);
        a0 = fmaf(v, bflo(u), a0); a1 = fmaf(v, bfhi(u), a1); den += v;
    }
    // combine halves (lane l <-> l^32): full row sums in every lane
    a0 += __shfl_xor(a0, 32);
    a1 += __shfl_xor(a1, 32);
    den += __shfl_xor(den, 32);

    float inv = (p1 > p0) ? 1.f / den : 0.f;
    float vh0 = a0 * inv, vh1 = a1 * inv;
    if (vh0 != vh0) vh0 = 0.f;
    if (vh1 != vh1) vh1 = 0.f;
    const int dcol = 64 + 2 * lh;
    vh0 += b[dcol]; vh1 += b[dcol + 1];
    float pp = vh0 * fc[dcol] + vh1 * fc[dcol + 1];
    #pragma unroll
    for (int off = 16; off; off >>= 1) pp += __shfl_xor(pp, off);
    float g = 1.f / (1.f + expf(-(pp + bfv[1])));
    float q0 = fmaxf(vh0, 0.f) + g * fminf(vh0, 0.f);
    float q1 = fmaxf(vh1, 0.f) + g * fminf(vh1, 0.f);
    q0 = (q0 > 0.f) ? q0 : ALPHA * q0;
    q1 = (q1 > 0.f) ? q1 : ALPHA * q1;
    if (half == 0) {
        float2 res; res.x = q0; res.y = q1;
        *(float2*)(out + (size_t)r * 128 + dcol) = res;
    }
}

// ---------------------------------------------------------------------------
// Colp-path kernels (fp32 fallback, race-free structure)
// ---------------------------------------------------------------------------
__global__ __launch_bounds__(256) void f11_spmm2_cp(
    const int* __restrict__ rp, const int* __restrict__ colp,
    const float* __restrict__ s_r, const float* __restrict__ s_c, // [2][N]
    const float* __restrict__ H,
    float* __restrict__ A0, float* __restrict__ A1, int N)
{
    long gid = (long)blockIdx.x * 256 + threadIdx.x;
    int r = (int)(gid >> 6), d = (int)(gid & 63);
    if (r >= N) return;
    int p0 = rp[r], p1 = rp[r + 1];
    const int sub = d >> 5;
    const float* scp = s_c + (size_t)sub * N;
    float sr = s_r[(size_t)sub * N + r];
    const float2* H2 = (const float2*)H;
    float a0 = 0.f, a1 = 0.f, den = 0.f;
    int p = p0;
    for (; p + 4 <= p1; p += 4) {
        int c0 = colp[p], c1 = colp[p + 1], c2 = colp[p + 2], c3 = colp[p + 3];
        float sc0 = scp[c0], sc1 = scp[c1], sc2 = scp[c2], sc3 = scp[c3];
        float2 h0 = H2[(size_t)c0 * 64 + d];
        float2 h1 = H2[(size_t)c1 * 64 + d];
        float2 h2 = H2[(size_t)c2 * 64 + d];
        float2 h3 = H2[(size_t)c3 * 64 + d];
        float e0 = sr + sc0; e0 = (e0 > 0.f) ? e0 : ALPHA * e0; float v0 = expf(e0);
        float e1 = sr + sc1; e1 = (e1 > 0.f) ? e1 : ALPHA * e1; float v1 = expf(e1);
        float e2 = sr + sc2; e2 = (e2 > 0.f) ? e2 : ALPHA * e2; float v2 = expf(e2);
        float e3 = sr + sc3; e3 = (e3 > 0.f) ? e3 : ALPHA * e3; float v3 = expf(e3);
        a0 = fmaf(v0, h0.x, a0); a1 = fmaf(v0, h0.y, a1); den += v0;
        a0 = fmaf(v1, h1.x, a0); a1 = fmaf(v1, h1.y, a1); den += v1;
        a0 = fmaf(v2, h2.x, a0); a1 = fmaf(v2, h2.y, a1); den += v2;
        a0 = fmaf(v3, h3.x, a0); a1 = fmaf(v3, h3.y, a1); den += v3;
    }
    for (; p < p1; ++p) {
        int c = colp[p];
        float e0 = sr + scp[c];
        e0 = (e0 > 0.f) ? e0 : ALPHA * e0;
        float v = expf(e0);
        float2 h = H2[(size_t)c * 64 + d];
        a0 = fmaf(v, h.x, a0); a1 = fmaf(v, h.y, a1); den += v;
    }
    float inv = (p1 > p0) ? 1.f / den : 0.f;
    int dcol = (2 * d) & 63;
    float2 res; res.x = a0 * inv; res.y = a1 * inv;
    float* dst = sub ? A1 : A0;
    *(float2*)(dst + (size_t)r * 64 + dcol) = res;
}

__global__ __launch_bounds__(256) void f9_spmm_fin(
    const int* __restrict__ rp, const int* __restrict__ colp,
    const float* __restrict__ s_r, const float* __restrict__ s_c,
    const float* __restrict__ src, int ss, int soff,
    const float* __restrict__ b, const float* __restrict__ fc,
    const float* __restrict__ bfv,
    float* __restrict__ out, int N, int sub)
{
    long gid = (long)blockIdx.x * 256 + threadIdx.x;
    int r = (int)(gid >> 6), d = (int)(gid & 63);
    if (r >= N) return;
    int p0 = rp[r], p1 = rp[r + 1];
    float sr = s_r[r];
    float acc = 0.f, den = 0.f;
    int p = p0;
    for (; p + 4 <= p1; p += 4) {
        int c0 = colp[p], c1 = colp[p + 1], c2 = colp[p + 2], c3 = colp[p + 3];
        float sc0 = s_c[c0], sc1 = s_c[c1], sc2 = s_c[c2], sc3 = s_c[c3];
        float s0 = src[(size_t)c0 * ss + soff + d];
        float s1 = src[(size_t)c1 * ss + soff + d];
        float s2 = src[(size_t)c2 * ss + soff + d];
        float s3 = src[(size_t)c3 * ss + soff + d];
        float e0 = sr + sc0; e0 = (e0 > 0.f) ? e0 : ALPHA * e0; float v0 = expf(e0);
        float e1 = sr + sc1; e1 = (e1 > 0.f) ? e1 : ALPHA * e1; float v1 = expf(e1);
        float e2 = sr + sc2; e2 = (e2 > 0.f) ? e2 : ALPHA * e2; float v2 = expf(e2);
        float e3 = sr + sc3; e3 = (e3 > 0.f) ? e3 : ALPHA * e3; float v3 = expf(e3);
        acc = fmaf(v0, s0, acc); den += v0;
        acc = fmaf(v1, s1, acc); den += v1;
        acc = fmaf(v2, s2, acc); den += v2;
        acc = fmaf(v3, s3, acc); den += v3;
    }
    for (; p < p1; ++p) {
        int c = colp[p];
        float ev = sr + s_c[c];
        ev = (ev > 0.f) ? ev : ALPHA * ev;
        float v = expf(ev);
        acc = fmaf(v, src[(size_t)c * ss + soff + d], acc);
        den += v;
    }
    float vh = (p1 > p0) ? acc / den : 0.f;
    if (vh != vh) vh = 0.f;
    vh += b[sub * 64 + d];
    float pp = vh * fc[sub * 64 + d];
    #pragma unroll
    for (int off = 32; off; off >>= 1) pp += __shfl_xor(pp, off);
    float g = 1.f / (1.f + expf(-(pp + bfv[sub])));
    float res = fmaxf(vh, 0.f) + g * fminf(vh, 0.f);
    res = (res > 0.f) ? res : ALPHA * res;
    out[(size_t)r * 128 + sub * 64 + d] = res;
}

__global__ __launch_bounds__(256) void f8_fin(
    const float* __restrict__ A,
    const float* __restrict__ b, const float* __restrict__ fc,
    const float* __restrict__ bfv,
    float* __restrict__ out, int N, int sub)
{
    long gid = (long)blockIdx.x * 256 + threadIdx.x;
    int n = (int)(gid >> 6), d = (int)(gid & 63);
    if (n >= N) return;
    float vh = A[(size_t)n * 64 + d];
    if (vh != vh) vh = 0.f;
    vh += b[sub * 64 + d];
    float p = vh * fc[sub * 64 + d];
    #pragma unroll
    for (int off = 32; off; off >>= 1) p += __shfl_xor(p, off);
    float g = 1.f / (1.f + expf(-(p + bfv[sub])));
    float res = fmaxf(vh, 0.f) + g * fminf(vh, 0.f);
    res = (res > 0.f) ? res : ALPHA * res;
    out[(size_t)n * 128 + sub * 64 + d] = res;
}

// ------------------- fallback (R7 atomic path) kernels ---------------------
__global__ __launch_bounds__(256) void f8_edge(
    const int* __restrict__ row, const int* __restrict__ col, int E,
    const float* __restrict__ s_r, const float* __restrict__ s_c,
    float* __restrict__ denom, int* __restrict__ cnt, int N)
{
    int e = blockIdx.x * 256 + threadIdx.x;
    if (e >= E) return;
    int r = row[e], c = col[e];
    if ((unsigned)r >= (unsigned)N || (unsigned)c >= (unsigned)N) return;
    if (cnt) atomicAdd(cnt + r, 1);
    #pragma unroll
    for (int i = 0; i < 2; ++i) {
        float ev = s_r[(size_t)i * N + r] + s_c[(size_t)i * N + c];
        ev = (ev > 0.f) ? ev : ALPHA * ev;
        atomicAdd(denom + (size_t)i * N + r, expf(ev));
    }
}
__global__ __launch_bounds__(256) void f7_spmm(
    const int* __restrict__ row, const int* __restrict__ col, int E,
    const float* __restrict__ s_r, const float* __restrict__ s_c,
    const float* __restrict__ denom,
    const float* __restrict__ out, int hcol,
    float* __restrict__ A, int N)
{
    long gid = (long)blockIdx.x * 256 + threadIdx.x;
    long wv  = gid >> 6;
    int  d   = (int)(gid & 63);
    long e0 = wv * 8, e1 = e0 + 8; if (e1 > E) e1 = E;
    for (long e = e0; e < e1; ++e) {
        int r = row[e], c = col[e];
        if ((unsigned)r >= (unsigned)N || (unsigned)c >= (unsigned)N) continue;
        float ev = s_r[r] + s_c[c];
        ev = (ev > 0.f) ? ev : ALPHA * ev;
        float v = expf(ev) / denom[r];
        atomicAdd(A + (size_t)r * 64 + d, v * out[(size_t)c * 128 + hcol + d]);
    }
}
__global__ __launch_bounds__(256) void f7_copy(
    const float* __restrict__ A, float* __restrict__ out, int cbase, int N)
{
    long gid = (long)blockIdx.x * 256 + threadIdx.x;
    long n = gid >> 6; int d = (int)(gid & 63);
    if (n >= N) return;
    out[(size_t)n * 128 + cbase + d] = A[(size_t)n * 64 + d];
}

extern "C" void kernel_launch(void* const* d_in, const int* in_sizes, int n_in,
                              void* d_out, int out_size, void* d_ws, size_t ws_size,
                              hipStream_t stream) {
    const float* x     = (const float*)d_in[0];
    const int*   ei    = (const int*)d_in[1];
    const float* W     = (const float*)d_in[2];
    const float* b     = (const float*)d_in[3];
    const float* fc    = (const float*)d_in[4];
    const float* bfv   = (const float*)d_in[5];
    const float* a_src = (const float*)d_in[6];
    const float* a_dst = (const float*)d_in[7];
    float* out = (float*)d_out;

    const int N = in_sizes[0] / 128;
    const int E = in_sizes[1] / 2;
    const int* row = ei;
    const int* col = ei + E;
    (void)n_in; (void)out_size;

    // --- Path P6 (MFMA + bf16 + rank + strided cnt, ~87 MB):
    //   Hb[N*128 u16] | A1b[N*64 u16] | WT[16384 u16] | rank[E int] |
    //   pk[E*8B] | s_r | s_c | rp | cnt[N*CSTRIDE] | scan tmp
    unsigned short* Hb   = (unsigned short*)d_ws;
    unsigned short* A1b  = Hb + (size_t)N * 128;
    unsigned short* WT   = A1b + (size_t)N * 64;
    int*            rank = (int*)(WT + 16384);
    uint2*          pk   = (uint2*)(rank + E);
    float*          s_rP = (float*)(pk + E);
    float*          s_cP = s_rP + 2 * (size_t)N;
    int*            rpP  = (int*)(s_cP + 2 * (size_t)N);
    int*            cntP = rpP + (N + 1);
    int*            bsumP = cntP + (size_t)N * CSTRIDE;
    int*            boffP = bsumP + 256;
    size_t          needP = (size_t)((char*)(boffP + 256) - (char*)d_ws);

    // --- Path A (colp fp32, ~67 MB): A0 | A1 | colp | s | rp | cnt | scan
    float* A0a   = (float*)d_ws;
    float* A1a   = A0a + (size_t)N * 64;
    int*   colpA = (int*)(A1a + (size_t)N * 64);
    float* s_rA  = (float*)(colpA + E);
    float* s_cA  = s_rA + 2 * (size_t)N;
    int*   rpA   = (int*)(s_cA + 2 * (size_t)N);
    int*   cntA  = rpA + (N + 1);
    int*   bsumA = cntA + N;
    int*   boffA = bsumA + 256;
    size_t needA = (size_t)((char*)(boffA + 256) - (char*)d_ws);

    const int g10 = 2 * ((N + 31) / 32);     // f10_h grid
    const int g14 = 2 * ((N + 63) / 64);     // f14_h grid (64 rows/block)
    const int eb  = (E + 255) / 256;
    const int rb  = (int)(((long)N * 64 + 255) / 256);
    const int nb  = (N + 1023) / 1024;

    if (ws_size >= needP) {
        // ===== Path P6 (R8 structure + strided-cnt atomics + wide fin2) ====
        hipMemsetAsync(cntP, 0, (size_t)N * CSTRIDE * sizeof(int), stream);
        f14_prep<<<eb, 256, 0, stream>>>(W, row, col, E, cntP, rank, WT, N);
        f14_h<<<g14, 256, 0, stream>>>(x, WT, a_src, a_dst, Hb, s_rP, s_cP, N);
        f16_scan1<<<nb, 256, 0, stream>>>(cntP, bsumP, N, CSTRIDE);
        f8_scan2<<<1, 256, 0, stream>>>(bsumP, boffP, nb);
        f16_scan3<<<nb, 256, 0, stream>>>(cntP, boffP, rpP, N, CSTRIDE);
        f14_scatter<<<eb, 256, 0, stream>>>(row, col, E, s_rP, s_cP, rpP,
                                            rank, pk, N);
        f12_spmm2<<<rb, 256, 0, stream>>>(rpP, pk, (const unsigned*)Hb,
                                          b, fc, bfv, A1b, out, N);
        f16_fin2<<<rb, 256, 0, stream>>>(rpP, pk, (const unsigned*)A1b,
                                         b, fc, bfv, out, N);
    } else if (ws_size >= needA) {
        // ======================= Path A (colp CSR) ========================
        hipMemsetAsync(cntA, 0, (size_t)N * sizeof(int), stream);
        f10_h<<<g10, 256, 0, stream>>>(x, W, a_src, a_dst, row, col, E, cntA,
                                       out, nullptr, s_rA, s_cA, N);
        f16_scan1<<<nb, 256, 0, stream>>>(cntA, bsumA, N, 1);
        f8_scan2<<<1, 256, 0, stream>>>(bsumA, boffA, nb);
        f16_scan3<<<nb, 256, 0, stream>>>(cntA, boffA, rpA, N, 1);
        f8_scatter<<<eb, 256, 0, stream>>>(row, col, E, cntA, colpA, N);
        f11_spmm2_cp<<<rb, 256, 0, stream>>>(rpA, colpA, s_rA, s_cA, out,
                                             A0a, A1a, N);
        f8_fin<<<rb, 256, 0, stream>>>(A0a, b, fc, bfv, out, N, 0);
        f9_spmm_fin<<<rb, 256, 0, stream>>>(rpA, colpA, s_rA + N, s_cA + N,
                                            A1a, 64, 0, b, fc, bfv, out, N, 1);
    } else {
        // ================= Path C (proven R7 atomic path) =================
        float* A     = (float*)d_ws;
        float* s_r   = A + (size_t)N * 64;
        float* s_c   = s_r + 2 * (size_t)N;
        float* denom = s_c + 2 * (size_t)N;
        const size_t planeB = (size_t)N * 64 * sizeof(float);
        const int sb = (int)(((((long)E + 7) / 8) * 64 + 255) / 256);
        hipMemsetAsync(denom, 0, 2 * (size_t)N * sizeof(float), stream);
        f10_h<<<g10, 256, 0, stream>>>(x, W, a_src, a_dst, row, col, E, nullptr,
                                       out, nullptr, s_r, s_c, N);
        f8_edge<<<eb, 256, 0, stream>>>(row, col, E, s_r, s_c, denom, nullptr, N);
        const float* s_r1 = s_r + N; const float* s_c1 = s_c + N; const float* den1 = denom + N;
        hipMemsetAsync(A, 0, planeB, stream);
        f7_spmm<<<sb, 256, 0, stream>>>(row, col, E, s_r, s_c, denom, out, 0, A, N);
        f8_fin<<<rb, 256, 0, stream>>>(A, b, fc, bfv, out, N, 0);
        hipMemsetAsync(A, 0, planeB, stream);
        f7_spmm<<<sb, 256, 0, stream>>>(row, col, E, s_r1, s_c1, den1, out, 64, A, N);
        f7_copy<<<rb, 256, 0, stream>>>(A, out, 64, N);
        hipMemsetAsync(A, 0, planeB, stream);
        f7_spmm<<<sb, 256, 0, stream>>>(row, col, E, s_r1, s_c1, den1, out, 64, A, N);
        f8_fin<<<rb, 256, 0, stream>>>(A, b, fc, bfv, out, N, 1);
    }
}

// Round 11
// 512.913 us; speedup vs baseline: 1.2247x; 1.1357x over previous
//
#include <hip/hip_runtime.h>

#define ALPHA 0.2f

typedef short bf16x8 __attribute__((ext_vector_type(8)));
typedef float f32x4  __attribute__((ext_vector_type(4)));

// bf16 helpers (RTN)
__device__ __forceinline__ unsigned short f2bf(float f) {
    unsigned u = __float_as_uint(f);
    u += 0x7FFFu + ((u >> 16) & 1u);
    return (unsigned short)(u >> 16);
}
__device__ __forceinline__ float bflo(unsigned u) {           // low ushort -> f32
    return __uint_as_float(u << 16);
}
__device__ __forceinline__ float bfhi(unsigned u) {           // high ushort -> f32
    return __uint_as_float(u & 0xFFFF0000u);
}

// ===========================================================================
// Path P7: radix-style CSR build — ZERO global atomics (R10 measured the
// fabric atomic limit at ~25G/s => 130us irreducible; LDS atomics instead).
// bucket = row >> 5 (32 rows/bucket), B = ceil(N/32) <= 4096.
// ===========================================================================

// p1: per-block LDS histogram over buckets -> hist[k*256 + b]; fused WT gen.
__global__ __launch_bounds__(256) void f17_p1(
    const int* __restrict__ row, const int* __restrict__ col, int E, int N,
    int B, int CH, int* __restrict__ hist,
    const float* __restrict__ W, unsigned short* __restrict__ WT)
{
    __shared__ int h[4096];
    const int b = blockIdx.x, t = threadIdx.x;
    for (int k = t; k < B; k += 256) h[k] = 0;
    int gidx = b * 256 + t;                    // WT transpose (16384 elems)
    if (gidx < 16384) {
        int i = gidx >> 13, c = (gidx >> 7) & 63, kk = gidx & 127;
        WT[gidx] = f2bf(W[i * 8192 + kk * 64 + c]);
    }
    __syncthreads();
    long base = (long)b * CH;
    long end  = base + CH; if (end > E) end = E;
    for (long e = base + t; e < end; e += 256) {
        int r = row[e], c = col[e];
        if ((unsigned)r < (unsigned)N && (unsigned)c < (unsigned)N)
            atomicAdd(&h[r >> 5], 1);          // LDS atomic
    }
    __syncthreads();
    for (int k = t; k < B; k += 256) hist[(size_t)k * 256 + b] = h[k];
}

// hist scan phase 1: 4096 elems/block (16/thread) -> chunk sums
__global__ __launch_bounds__(256) void f17_sc1(
    const int* __restrict__ h, int* __restrict__ bsums, int M)
{
    __shared__ int sdat[256];
    int t = threadIdx.x, blk = blockIdx.x;
    long base = (long)blk * 4096 + t * 16;
    int s = 0;
    #pragma unroll
    for (int j = 0; j < 16; ++j) {
        long idx = base + j;
        if (idx < M) s += h[idx];
    }
    sdat[t] = s; __syncthreads();
    for (int o = 1; o < 256; o <<= 1) {
        int add = (t >= o) ? sdat[t - o] : 0;
        __syncthreads();
        sdat[t] += add;
        __syncthreads();
    }
    if (t == 255) bsums[blk] = sdat[255];
}
// phase 2 (chunk-sum exclusive scan, nb<=256)
__global__ __launch_bounds__(256) void f8_scan2(
    const int* __restrict__ bsums, int* __restrict__ boffs, int nb)
{
    __shared__ int sdat[256];
    int t = threadIdx.x;
    int v = (t < nb) ? bsums[t] : 0;
    sdat[t] = v; __syncthreads();
    for (int o = 1; o < 256; o <<= 1) {
        int add = (t >= o) ? sdat[t - o] : 0;
        __syncthreads();
        sdat[t] += add;
        __syncthreads();
    }
    if (t < nb) boffs[t] = sdat[t] - v;   // exclusive
}
// hist scan phase 3: exclusive scan in place; bstart[k] at (k,0); bstart[B]=tot
__global__ __launch_bounds__(256) void f17_sc3(
    int* __restrict__ h, const int* __restrict__ boffs,
    int* __restrict__ bstart, int M)
{
    __shared__ int sdat[256];
    int t = threadIdx.x, blk = blockIdx.x;
    long base = (long)blk * 4096 + t * 16;
    int v[16]; int s = 0;
    #pragma unroll
    for (int j = 0; j < 16; ++j) {
        long idx = base + j;
        v[j] = (idx < M) ? h[idx] : 0;
        s += v[j];
    }
    sdat[t] = s; __syncthreads();
    for (int o = 1; o < 256; o <<= 1) {
        int add = (t >= o) ? sdat[t - o] : 0;
        __syncthreads();
        sdat[t] += add;
        __syncthreads();
    }
    int excl = boffs[blk] + sdat[t] - s;
    #pragma unroll
    for (int j = 0; j < 16; ++j) {
        long idx = base + j;
        if (idx < M) {
            h[idx] = excl;
            if ((idx & 255) == 0) bstart[idx >> 8] = excl;
            if (idx == M - 1)     bstart[M >> 8]   = excl + v[j];
            excl += v[j];
        }
    }
}

// p2: bucket-scatter with LDS cursors; computes per-edge exps (bf16 pair).
// Record: x = col | (row&31)<<25 ; y = {exp1:bf16 | exp0:bf16}.
__global__ __launch_bounds__(256) void f17_p2(
    const int* __restrict__ row, const int* __restrict__ col, int E, int N,
    int B, int CH, const int* __restrict__ hist,
    const float* __restrict__ s_r, const float* __restrict__ s_c, // [2][N]
    uint2* __restrict__ pkA)
{
    __shared__ int cur[4096];
    const int b = blockIdx.x, t = threadIdx.x;
    for (int k = t; k < B; k += 256) cur[k] = hist[(size_t)k * 256 + b];
    __syncthreads();
    long base = (long)b * CH;
    long end  = base + CH; if (end > E) end = E;
    for (long e = base + t; e < end; e += 256) {
        int r = row[e], c = col[e];
        if ((unsigned)r >= (unsigned)N || (unsigned)c >= (unsigned)N) continue;
        float e0 = s_r[r] + s_c[c];
        float e1 = s_r[(size_t)N + r] + s_c[(size_t)N + c];
        e0 = (e0 > 0.f) ? e0 : ALPHA * e0;
        e1 = (e1 > 0.f) ? e1 : ALPHA * e1;
        unsigned py = ((unsigned)f2bf(expf(e1)) << 16) | (unsigned)f2bf(expf(e0));
        int pos = atomicAdd(&cur[r >> 5], 1);  // LDS atomic, global offset base
        uint2 m; m.x = (unsigned)c | ((unsigned)(r & 31) << 25); m.y = py;
        pkA[pos] = m;
    }
}

// p3: one block per bucket; 32-row LDS histogram -> rp + within-bucket
// scatter pkA -> pkB (strips the row-low5 bits). No global atomics.
__global__ __launch_bounds__(256) void f17_p3(
    const uint2* __restrict__ pkA, const int* __restrict__ bstart,
    int N, int B, uint2* __restrict__ pkB, int* __restrict__ rp)
{
    __shared__ int h32[32], ex33[33], cur32[32];
    const int k = blockIdx.x, t = threadIdx.x;
    const int p0 = bstart[k], p1 = bstart[k + 1];
    if (t < 32) h32[t] = 0;
    __syncthreads();
    for (int p = p0 + t; p < p1; p += 256)
        atomicAdd(&h32[pkA[p].x >> 25], 1);
    __syncthreads();
    if (t == 0) {
        int s = 0;
        #pragma unroll
        for (int j = 0; j < 32; ++j) { ex33[j] = s; s += h32[j]; }
        ex33[32] = s;
    }
    __syncthreads();
    if (t < 32) {
        int r = k * 32 + t;
        if (r < N) rp[r] = p0 + ex33[t];
        cur32[t] = p0 + ex33[t];
    }
    if (k == B - 1 && t == 0) rp[N] = p1;      // total valid edges
    __syncthreads();
    for (int p = p0 + t; p < p1; p += 256) {
        uint2 m = pkA[p];
        int pos = atomicAdd(&cur32[m.x >> 25], 1);
        uint2 o; o.x = m.x & 0x01FFFFFFu; o.y = m.y;
        pkB[pos] = o;
    }
}

// ---------------------------------------------------------------------------
// f14_h: MFMA GEMM h = x @ W[i] (x -> bf16 in-register), fused s_r/s_c dots,
// LDS-transposed vectorized Hb write. (R8/R10-proven.)
// Fragment layouts (m89-verified family): A: row=l&15, k=(l>>4)*8+j;
// B: col=l&15, k=(l>>4)*8+j; D: col=l&15, row=(l>>4)*4+reg.
// ---------------------------------------------------------------------------
__global__ __launch_bounds__(256) void f14_h(
    const float* __restrict__ x,             // N x 128 fp32
    const unsigned short* __restrict__ WT,   // [2][64][128] bf16
    const float* __restrict__ a_src, const float* __restrict__ a_dst,
    unsigned short* __restrict__ Hb,         // N x 128 bf16 (row-major)
    float* __restrict__ s_r, float* __restrict__ s_c, int N)
{
    __shared__ __align__(16) unsigned short hs[4][16][72];  // 9KB; +8 pad/row
    const int t  = threadIdx.x;
    const int wv = t >> 6, l = t & 63;
    const int i  = blockIdx.x & 1;
    const int n0 = (blockIdx.x >> 1) * 64 + wv * 16;
    const int lm = l & 15, lg = l >> 4;

    int arow = n0 + lm; if (arow >= N) arow = N - 1;       // clamped; stores guarded
    const float* xr = x + (size_t)arow * 128 + lg * 8;
    bf16x8 af[4];
    #pragma unroll
    for (int ks = 0; ks < 4; ++ks) {
        float4 u0 = *(const float4*)(xr + ks * 32);
        float4 u1 = *(const float4*)(xr + ks * 32 + 4);
        bf16x8 a;
        a[0] = (short)f2bf(u0.x); a[1] = (short)f2bf(u0.y);
        a[2] = (short)f2bf(u0.z); a[3] = (short)f2bf(u0.w);
        a[4] = (short)f2bf(u1.x); a[5] = (short)f2bf(u1.y);
        a[6] = (short)f2bf(u1.z); a[7] = (short)f2bf(u1.w);
        af[ks] = a;
    }

    const unsigned short* wr = WT + ((size_t)i * 64 + lm) * 128 + lg * 8;
    f32x4 zero = {0.f, 0.f, 0.f, 0.f};
    f32x4 acc[4];
    #pragma unroll
    for (int ct = 0; ct < 4; ++ct) {
        acc[ct] = zero;
        #pragma unroll
        for (int ks = 0; ks < 4; ++ks) {
            bf16x8 bf = *(const bf16x8*)(wr + ct * 16 * 128 + ks * 32);
            acc[ct] = __builtin_amdgcn_mfma_f32_16x16x32_bf16(af[ks], bf, acc[ct], 0, 0, 0);
        }
    }

    float asv[4], adv[4];
    #pragma unroll
    for (int ct = 0; ct < 4; ++ct) {
        asv[ct] = a_src[i * 64 + ct * 16 + lm];
        adv[ct] = a_dst[i * 64 + ct * 16 + lm];
    }
    #pragma unroll
    for (int reg = 0; reg < 4; ++reg) {
        float vr = 0.f, vc = 0.f;
        #pragma unroll
        for (int ct = 0; ct < 4; ++ct) {
            vr = fmaf(acc[ct][reg], asv[ct], vr);
            vc = fmaf(acc[ct][reg], adv[ct], vc);
        }
        #pragma unroll
        for (int off = 8; off; off >>= 1) {
            vr += __shfl_xor(vr, off);
            vc += __shfl_xor(vc, off);
        }
        int n = n0 + lg * 4 + reg;
        if (lm == 0 && n < N) {
            s_r[(size_t)i * N + n] = vr;
            s_c[(size_t)i * N + n] = vc;
        }
    }

    // H write via per-wave LDS transpose (no barrier: same-wave produce/consume)
    #pragma unroll
    for (int ct = 0; ct < 4; ++ct)
        #pragma unroll
        for (int reg = 0; reg < 4; ++reg)
            hs[wv][lg * 4 + reg][ct * 16 + lm] = f2bf(acc[ct][reg]);
    #pragma unroll
    for (int j = 0; j < 2; ++j) {
        int r = (l >> 3) + j * 8;
        int n = n0 + r;
        if (n < N) {
            int g = (l & 7) * 8;
            *(uint4*)(Hb + (size_t)n * 128 + i * 64 + g) =
                *(const uint4*)&hs[wv][r][g];
        }
    }
}

// ---------------------------------------------------------------------------
// f10_h: LDS-tiled vector GEMM (kept for fp32 fallback paths A/C)
// ---------------------------------------------------------------------------
__global__ __launch_bounds__(256) void f10_h(
    const float* __restrict__ x, const float* __restrict__ W,
    const float* __restrict__ a_src, const float* __restrict__ a_dst,
    const int* __restrict__ row, const int* __restrict__ col, int E,
    int* __restrict__ cnt,
    float* __restrict__ Hf, unsigned short* __restrict__ Hb,
    float* __restrict__ s_r, float* __restrict__ s_c, int N)
{
    __shared__ __align__(16) float ws[128][64];
    __shared__ __align__(16) float xs[128][36];
    const int t  = threadIdx.x;
    const int i  = blockIdx.x & 1;
    const int n0 = (blockIdx.x >> 1) * 32;

    if (cnt) {
        const long total = (long)gridDim.x * 256;
        for (long e = (long)blockIdx.x * 256 + t; e < E; e += total) {
            int r = row[e], c = col[e];
            if ((unsigned)r < (unsigned)N && (unsigned)c < (unsigned)N)
                atomicAdd(cnt + r, 1);
        }
    }
    {
        const float* wp = W + (size_t)i * 8192;
        #pragma unroll
        for (int j = 0; j < 8; ++j) {
            int idx = t + j * 256;
            int k   = idx >> 4;
            int c4  = (idx & 15) * 4;
            *(float4*)&ws[k][c4] = *(const float4*)(wp + k * 64 + c4);
        }
    }
    {
        int r = t >> 3;
        int n = n0 + r;
        #pragma unroll
        for (int j = 0; j < 4; ++j) {
            int k0 = ((t & 7) + j * 8) * 4;
            float4 v = (n < N) ? *(const float4*)(x + (size_t)n * 128 + k0)
                               : make_float4(0.f, 0.f, 0.f, 0.f);
            xs[k0 + 0][r] = v.x; xs[k0 + 1][r] = v.y;
            xs[k0 + 2][r] = v.z; xs[k0 + 3][r] = v.w;
        }
    }
    __syncthreads();

    const int tc = t & 31, tn = t >> 5;
    float acc[4][2] = {};
    #pragma unroll 8
    for (int k = 0; k < 128; ++k) {
        float4 xv = *(const float4*)&xs[k][tn * 4];
        float2 wv = *(const float2*)&ws[k][tc * 2];
        acc[0][0] = fmaf(xv.x, wv.x, acc[0][0]);
        acc[0][1] = fmaf(xv.x, wv.y, acc[0][1]);
        acc[1][0] = fmaf(xv.y, wv.x, acc[1][0]);
        acc[1][1] = fmaf(xv.y, wv.y, acc[1][1]);
        acc[2][0] = fmaf(xv.z, wv.x, acc[2][0]);
        acc[2][1] = fmaf(xv.z, wv.y, acc[2][1]);
        acc[3][0] = fmaf(xv.w, wv.x, acc[3][0]);
        acc[3][1] = fmaf(xv.w, wv.y, acc[3][1]);
    }

    const float2 asv = *(const float2*)(a_src + i * 64 + tc * 2);
    const float2 adv = *(const float2*)(a_dst + i * 64 + tc * 2);
    #pragma unroll
    for (int a = 0; a < 4; ++a) {
        int n = n0 + tn * 4 + a;
        if (n >= N) break;
        float2 hv; hv.x = acc[a][0]; hv.y = acc[a][1];
        if (Hf) *(float2*)(Hf + (size_t)n * 128 + i * 64 + tc * 2) = hv;
        if (Hb) {
            ushort2 hb; hb.x = f2bf(hv.x); hb.y = f2bf(hv.y);
            *(ushort2*)(Hb + (size_t)n * 128 + (i * 32 + tc) * 2) = hb;
        }
        float pr = hv.x * asv.x + hv.y * asv.y;
        float pc = hv.x * adv.x + hv.y * adv.y;
        #pragma unroll
        for (int off = 16; off; off >>= 1) {
            pr += __shfl_xor(pr, off);
            pc += __shfl_xor(pc, off);
        }
        if (tc == 0) {
            s_r[(size_t)i * N + n] = pr;
            s_c[(size_t)i * N + n] = pc;
        }
    }
}

// --------------- Path-A scans (row-granular cnt) ---------------------------
__global__ __launch_bounds__(256) void f16_scan1(
    const int* __restrict__ cnt, int* __restrict__ bsums, int N, int cs)
{
    __shared__ int sdat[256];
    int t = threadIdx.x, b = blockIdx.x;
    int s = 0;
    #pragma unroll
    for (int j = 0; j < 4; ++j) {
        int idx = b * 1024 + t * 4 + j;
        if (idx < N) s += cnt[(size_t)idx * cs];
    }
    sdat[t] = s; __syncthreads();
    for (int o = 1; o < 256; o <<= 1) {
        int add = (t >= o) ? sdat[t - o] : 0;
        __syncthreads();
        sdat[t] += add;
        __syncthreads();
    }
    if (t == 255) bsums[b] = sdat[255];
}
__global__ __launch_bounds__(256) void f16_scan3(
    int* __restrict__ cnt, const int* __restrict__ boffs,
    int* __restrict__ rp, int N, int cs)
{
    __shared__ int sdat[256];
    int t = threadIdx.x, b = blockIdx.x;
    int v[4]; int s = 0;
    #pragma unroll
    for (int j = 0; j < 4; ++j) {
        int idx = b * 1024 + t * 4 + j;
        v[j] = (idx < N) ? cnt[(size_t)idx * cs] : 0;
        s += v[j];
    }
    sdat[t] = s; __syncthreads();
    for (int o = 1; o < 256; o <<= 1) {
        int add = (t >= o) ? sdat[t - o] : 0;
        __syncthreads();
        sdat[t] += add;
        __syncthreads();
    }
    int excl = boffs[b] + sdat[t] - s;
    #pragma unroll
    for (int j = 0; j < 4; ++j) {
        int idx = b * 1024 + t * 4 + j;
        if (idx < N) {
            rp[idx] = excl;
            if (cs == 1) cnt[idx] = excl;     // cursor copy (fallback path only)
            if (idx == N - 1) rp[N] = excl + v[j];
            excl += v[j];
        }
    }
}

// legacy scatter (colp only) for the mid path
__global__ __launch_bounds__(256) void f8_scatter(
    const int* __restrict__ row, const int* __restrict__ col, int E,
    int* __restrict__ cur, int* __restrict__ colp, int N)
{
    int e = blockIdx.x * 256 + threadIdx.x;
    if (e >= E) return;
    int r = row[e], c = col[e];
    if ((unsigned)r >= (unsigned)N || (unsigned)c >= (unsigned)N) return;
    int pos = atomicAdd(cur + r, 1);
    colp[pos] = c;
}

// ---------------------------------------------------------------------------
// f12_spmm2: dual-subhead hop-1 SpMM. bf16 H gathers, 8B pk, 8x pipeline,
// inline denominator. Sub0 lanes: fused NodeAdaptiveEncoder -> out[0:64];
// sub1 lanes -> A1b (bf16).
// ---------------------------------------------------------------------------
__global__ __launch_bounds__(256) void f12_spmm2(
    const int* __restrict__ rp, const uint2* __restrict__ pk,
    const unsigned* __restrict__ Hb,           // N x 64 uints (bf16 pairs)
    const float* __restrict__ b, const float* __restrict__ fc,
    const float* __restrict__ bfv,
    unsigned short* __restrict__ A1b, float* __restrict__ out, int N)
{
    long gid = (long)blockIdx.x * 256 + threadIdx.x;
    int r = (int)(gid >> 6), d = (int)(gid & 63);
    if (r >= N) return;
    int p0 = rp[r], p1 = rp[r + 1];
    const int sub = d >> 5;
    float a0 = 0.f, a1 = 0.f, den = 0.f;
    int p = p0;
    for (; p + 8 <= p1; p += 8) {
        uint2 m0 = pk[p],     m1 = pk[p + 1], m2 = pk[p + 2], m3 = pk[p + 3];
        uint2 m4 = pk[p + 4], m5 = pk[p + 5], m6 = pk[p + 6], m7 = pk[p + 7];
        unsigned u0 = Hb[(size_t)m0.x * 64 + d];
        unsigned u1 = Hb[(size_t)m1.x * 64 + d];
        unsigned u2 = Hb[(size_t)m2.x * 64 + d];
        unsigned u3 = Hb[(size_t)m3.x * 64 + d];
        unsigned u4 = Hb[(size_t)m4.x * 64 + d];
        unsigned u5 = Hb[(size_t)m5.x * 64 + d];
        unsigned u6 = Hb[(size_t)m6.x * 64 + d];
        unsigned u7 = Hb[(size_t)m7.x * 64 + d];
        float v0 = sub ? bfhi(m0.y) : bflo(m0.y);
        float v1 = sub ? bfhi(m1.y) : bflo(m1.y);
        float v2 = sub ? bfhi(m2.y) : bflo(m2.y);
        float v3 = sub ? bfhi(m3.y) : bflo(m3.y);
        float v4 = sub ? bfhi(m4.y) : bflo(m4.y);
        float v5 = sub ? bfhi(m5.y) : bflo(m5.y);
        float v6 = sub ? bfhi(m6.y) : bflo(m6.y);
        float v7 = sub ? bfhi(m7.y) : bflo(m7.y);
        a0 = fmaf(v0, bflo(u0), a0); a1 = fmaf(v0, bfhi(u0), a1); den += v0;
        a0 = fmaf(v1, bflo(u1), a0); a1 = fmaf(v1, bfhi(u1), a1); den += v1;
        a0 = fmaf(v2, bflo(u2), a0); a1 = fmaf(v2, bfhi(u2), a1); den += v2;
        a0 = fmaf(v3, bflo(u3), a0); a1 = fmaf(v3, bfhi(u3), a1); den += v3;
        a0 = fmaf(v4, bflo(u4), a0); a1 = fmaf(v4, bfhi(u4), a1); den += v4;
        a0 = fmaf(v5, bflo(u5), a0); a1 = fmaf(v5, bfhi(u5), a1); den += v5;
        a0 = fmaf(v6, bflo(u6), a0); a1 = fmaf(v6, bfhi(u6), a1); den += v6;
        a0 = fmaf(v7, bflo(u7), a0); a1 = fmaf(v7, bfhi(u7), a1); den += v7;
    }
    for (; p < p1; ++p) {
        uint2 m = pk[p];
        unsigned u = Hb[(size_t)m.x * 64 + d];
        float v = sub ? bfhi(m.y) : bflo(m.y);
        a0 = fmaf(v, bflo(u), a0); a1 = fmaf(v, bfhi(u), a1); den += v;
    }
    float inv = (p1 > p0) ? 1.f / den : 0.f;
    float r0 = a0 * inv, r1 = a1 * inv;
    if (sub) {
        ushort2 res; res.x = f2bf(r0); res.y = f2bf(r1);
        *(ushort2*)(A1b + (size_t)r * 64 + (d - 32) * 2) = res;
    } else {
        int dcol = 2 * d;
        float vh0 = (r0 != r0) ? 0.f : r0;
        float vh1 = (r1 != r1) ? 0.f : r1;
        float2 bb = *(const float2*)(b + dcol);
        float2 ff = *(const float2*)(fc + dcol);
        vh0 += bb.x; vh1 += bb.y;
        float pp = vh0 * ff.x + vh1 * ff.y;
        #pragma unroll
        for (int off = 16; off; off >>= 1) pp += __shfl_xor(pp, off);
        float g = 1.f / (1.f + expf(-(pp + bfv[0])));
        float q0 = fmaxf(vh0, 0.f) + g * fminf(vh0, 0.f);
        float q1 = fmaxf(vh1, 0.f) + g * fminf(vh1, 0.f);
        q0 = (q0 > 0.f) ? q0 : ALPHA * q0;
        q1 = (q1 > 0.f) ? q1 : ALPHA * q1;
        float2 res; res.x = q0; res.y = q1;
        *(float2*)(out + (size_t)r * 128 + dcol) = res;
    }
}

// ---------------------------------------------------------------------------
// f16_fin2: sub1 hop-2 SpMM, dual-edge wave layout (R10-proven).
// ---------------------------------------------------------------------------
__global__ __launch_bounds__(256) void f16_fin2(
    const int* __restrict__ rp, const uint2* __restrict__ pk,
    const unsigned* __restrict__ A1u,          // N x 32 uints (bf16 pairs)
    const float* __restrict__ b, const float* __restrict__ fc,
    const float* __restrict__ bfv,
    float* __restrict__ out, int N)
{
    long gid = (long)blockIdx.x * 256 + threadIdx.x;
    int r = (int)(gid >> 6), l = (int)(gid & 63);
    if (r >= N) return;
    const int half = l >> 5, lh = l & 31;
    int p0 = rp[r], p1 = rp[r + 1];
    float a0 = 0.f, a1 = 0.f, den = 0.f;
    int p = p0;
    for (; p + 8 <= p1; p += 8) {      // 8 edges/iter, 4 per half
        uint2 m0 = pk[p + half],     m1 = pk[p + 2 + half];
        uint2 m2 = pk[p + 4 + half], m3 = pk[p + 6 + half];
        unsigned u0 = A1u[(size_t)m0.x * 32 + lh];
        unsigned u1 = A1u[(size_t)m1.x * 32 + lh];
        unsigned u2 = A1u[(size_t)m2.x * 32 + lh];
        unsigned u3 = A1u[(size_t)m3.x * 32 + lh];
        float v0 = bfhi(m0.y), v1 = bfhi(m1.y);
        float v2 = bfhi(m2.y), v3 = bfhi(m3.y);
        a0 = fmaf(v0, bflo(u0), a0); a1 = fmaf(v0, bfhi(u0), a1); den += v0;
        a0 = fmaf(v1, bflo(u1), a0); a1 = fmaf(v1, bfhi(u1), a1); den += v1;
        a0 = fmaf(v2, bflo(u2), a0); a1 = fmaf(v2, bfhi(u2), a1); den += v2;
        a0 = fmaf(v3, bflo(u3), a0); a1 = fmaf(v3, bfhi(u3), a1); den += v3;
    }
    for (; p + 2 <= p1; p += 2) {
        uint2 m = pk[p + half];
        unsigned u = A1u[(size_t)m.x * 32 + lh];
        float v = bfhi(m.y);
        a0 = fmaf(v, bflo(u), a0); a1 = fmaf(v, bfhi(u), a1); den += v;
    }
    if (p < p1 && half == 0) {          // odd remainder: half 0 only
        uint2 m = pk[p];
        unsigned u = A1u[(size_t)m.x * 32 + lh];
        float v = bfhi(m.y);
        a0 = fmaf(v, bflo(u), a0); a1 = fmaf(v, bfhi(u), a1); den += v;
    }
    a0 += __shfl_xor(a0, 32);
    a1 += __shfl_xor(a1, 32);
    den += __shfl_xor(den, 32);

    float inv = (p1 > p0) ? 1.f / den : 0.f;
    float vh0 = a0 * inv, vh1 = a1 * inv;
    if (vh0 != vh0) vh0 = 0.f;
    if (vh1 != vh1) vh1 = 0.f;
    const int dcol = 64 + 2 * lh;
    vh0 += b[dcol]; vh1 += b[dcol + 1];
    float pp = vh0 * fc[dcol] + vh1 * fc[dcol + 1];
    #pragma unroll
    for (int off = 16; off; off >>= 1) pp += __shfl_xor(pp, off);
    float g = 1.f / (1.f + expf(-(pp + bfv[1])));
    float q0 = fmaxf(vh0, 0.f) + g * fminf(vh0, 0.f);
    float q1 = fmaxf(vh1, 0.f) + g * fminf(vh1, 0.f);
    q0 = (q0 > 0.f) ? q0 : ALPHA * q0;
    q1 = (q1 > 0.f) ? q1 : ALPHA * q1;
    if (half == 0) {
        float2 res; res.x = q0; res.y = q1;
        *(float2*)(out + (size_t)r * 128 + dcol) = res;
    }
}

// ---------------------------------------------------------------------------
// Colp-path kernels (fp32 fallback, race-free structure)
// ---------------------------------------------------------------------------
__global__ __launch_bounds__(256) void f11_spmm2_cp(
    const int* __restrict__ rp, const int* __restrict__ colp,
    const float* __restrict__ s_r, const float* __restrict__ s_c, // [2][N]
    const float* __restrict__ H,
    float* __restrict__ A0, float* __restrict__ A1, int N)
{
    long gid = (long)blockIdx.x * 256 + threadIdx.x;
    int r = (int)(gid >> 6), d = (int)(gid & 63);
    if (r >= N) return;
    int p0 = rp[r], p1 = rp[r + 1];
    const int sub = d >> 5;
    const float* scp = s_c + (size_t)sub * N;
    float sr = s_r[(size_t)sub * N + r];
    const float2* H2 = (const float2*)H;
    float a0 = 0.f, a1 = 0.f, den = 0.f;
    int p = p0;
    for (; p + 4 <= p1; p += 4) {
        int c0 = colp[p], c1 = colp[p + 1], c2 = colp[p + 2], c3 = colp[p + 3];
        float sc0 = scp[c0], sc1 = scp[c1], sc2 = scp[c2], sc3 = scp[c3];
        float2 h0 = H2[(size_t)c0 * 64 + d];
        float2 h1 = H2[(size_t)c1 * 64 + d];
        float2 h2 = H2[(size_t)c2 * 64 + d];
        float2 h3 = H2[(size_t)c3 * 64 + d];
        float e0 = sr + sc0; e0 = (e0 > 0.f) ? e0 : ALPHA * e0; float v0 = expf(e0);
        float e1 = sr + sc1; e1 = (e1 > 0.f) ? e1 : ALPHA * e1; float v1 = expf(e1);
        float e2 = sr + sc2; e2 = (e2 > 0.f) ? e2 : ALPHA * e2; float v2 = expf(e2);
        float e3 = sr + sc3; e3 = (e3 > 0.f) ? e3 : ALPHA * e3; float v3 = expf(e3);
        a0 = fmaf(v0, h0.x, a0); a1 = fmaf(v0, h0.y, a1); den += v0;
        a0 = fmaf(v1, h1.x, a0); a1 = fmaf(v1, h1.y, a1); den += v1;
        a0 = fmaf(v2, h2.x, a0); a1 = fmaf(v2, h2.y, a1); den += v2;
        a0 = fmaf(v3, h3.x, a0); a1 = fmaf(v3, h3.y, a1); den += v3;
    }
    for (; p < p1; ++p) {
        int c = colp[p];
        float e0 = sr + scp[c];
        e0 = (e0 > 0.f) ? e0 : ALPHA * e0;
        float v = expf(e0);
        float2 h = H2[(size_t)c * 64 + d];
        a0 = fmaf(v, h.x, a0); a1 = fmaf(v, h.y, a1); den += v;
    }
    float inv = (p1 > p0) ? 1.f / den : 0.f;
    int dcol = (2 * d) & 63;
    float2 res; res.x = a0 * inv; res.y = a1 * inv;
    float* dst = sub ? A1 : A0;
    *(float2*)(dst + (size_t)r * 64 + dcol) = res;
}

__global__ __launch_bounds__(256) void f9_spmm_fin(
    const int* __restrict__ rp, const int* __restrict__ colp,
    const float* __restrict__ s_r, const float* __restrict__ s_c,
    const float* __restrict__ src, int ss, int soff,
    const float* __restrict__ b, const float* __restrict__ fc,
    const float* __restrict__ bfv,
    float* __restrict__ out, int N, int sub)
{
    long gid = (long)blockIdx.x * 256 + threadIdx.x;
    int r = (int)(gid >> 6), d = (int)(gid & 63);
    if (r >= N) return;
    int p0 = rp[r], p1 = rp[r + 1];
    float sr = s_r[r];
    float acc = 0.f, den = 0.f;
    int p = p0;
    for (; p + 4 <= p1; p += 4) {
        int c0 = colp[p], c1 = colp[p + 1], c2 = colp[p + 2], c3 = colp[p + 3];
        float sc0 = s_c[c0], sc1 = s_c[c1], sc2 = s_c[c2], sc3 = s_c[c3];
        float s0 = src[(size_t)c0 * ss + soff + d];
        float s1 = src[(size_t)c1 * ss + soff + d];
        float s2 = src[(size_t)c2 * ss + soff + d];
        float s3 = src[(size_t)c3 * ss + soff + d];
        float e0 = sr + sc0; e0 = (e0 > 0.f) ? e0 : ALPHA * e0; float v0 = expf(e0);
        float e1 = sr + sc1; e1 = (e1 > 0.f) ? e1 : ALPHA * e1; float v1 = expf(e1);
        float e2 = sr + sc2; e2 = (e2 > 0.f) ? e2 : ALPHA * e2; float v2 = expf(e2);
        float e3 = sr + sc3; e3 = (e3 > 0.f) ? e3 : ALPHA * e3; float v3 = expf(e3);
        acc = fmaf(v0, s0, acc); den += v0;
        acc = fmaf(v1, s1, acc); den += v1;
        acc = fmaf(v2, s2, acc); den += v2;
        acc = fmaf(v3, s3, acc); den += v3;
    }
    for (; p < p1; ++p) {
        int c = colp[p];
        float ev = sr + s_c[c];
        ev = (ev > 0.f) ? ev : ALPHA * ev;
        float v = expf(ev);
        acc = fmaf(v, src[(size_t)c * ss + soff + d], acc);
        den += v;
    }
    float vh = (p1 > p0) ? acc / den : 0.f;
    if (vh != vh) vh = 0.f;
    vh += b[sub * 64 + d];
    float pp = vh * fc[sub * 64 + d];
    #pragma unroll
    for (int off = 32; off; off >>= 1) pp += __shfl_xor(pp, off);
    float g = 1.f / (1.f + expf(-(pp + bfv[sub])));
    float res = fmaxf(vh, 0.f) + g * fminf(vh, 0.f);
    res = (res > 0.f) ? res : ALPHA * res;
    out[(size_t)r * 128 + sub * 64 + d] = res;
}

__global__ __launch_bounds__(256) void f8_fin(
    const float* __restrict__ A,
    const float* __restrict__ b, const float* __restrict__ fc,
    const float* __restrict__ bfv,
    float* __restrict__ out, int N, int sub)
{
    long gid = (long)blockIdx.x * 256 + threadIdx.x;
    int n = (int)(gid >> 6), d = (int)(gid & 63);
    if (n >= N) return;
    float vh = A[(size_t)n * 64 + d];
    if (vh != vh) vh = 0.f;
    vh += b[sub * 64 + d];
    float p = vh * fc[sub * 64 + d];
    #pragma unroll
    for (int off = 32; off; off >>= 1) p += __shfl_xor(p, off);
    float g = 1.f / (1.f + expf(-(p + bfv[sub])));
    float res = fmaxf(vh, 0.f) + g * fminf(vh, 0.f);
    res = (res > 0.f) ? res : ALPHA * res;
    out[(size_t)n * 128 + sub * 64 + d] = res;
}

// ------------------- fallback (R7 atomic path) kernels ---------------------
__global__ __launch_bounds__(256) void f8_edge(
    const int* __restrict__ row, const int* __restrict__ col, int E,
    const float* __restrict__ s_r, const float* __restrict__ s_c,
    float* __restrict__ denom, int* __restrict__ cnt, int N)
{
    int e = blockIdx.x * 256 + threadIdx.x;
    if (e >= E) return;
    int r = row[e], c = col[e];
    if ((unsigned)r >= (unsigned)N || (unsigned)c >= (unsigned)N) return;
    if (cnt) atomicAdd(cnt + r, 1);
    #pragma unroll
    for (int i = 0; i < 2; ++i) {
        float ev = s_r[(size_t)i * N + r] + s_c[(size_t)i * N + c];
        ev = (ev > 0.f) ? ev : ALPHA * ev;
        atomicAdd(denom + (size_t)i * N + r, expf(ev));
    }
}
__global__ __launch_bounds__(256) void f7_spmm(
    const int* __restrict__ row, const int* __restrict__ col, int E,
    const float* __restrict__ s_r, const float* __restrict__ s_c,
    const float* __restrict__ denom,
    const float* __restrict__ out, int hcol,
    float* __restrict__ A, int N)
{
    long gid = (long)blockIdx.x * 256 + threadIdx.x;
    long wv  = gid >> 6;
    int  d   = (int)(gid & 63);
    long e0 = wv * 8, e1 = e0 + 8; if (e1 > E) e1 = E;
    for (long e = e0; e < e1; ++e) {
        int r = row[e], c = col[e];
        if ((unsigned)r >= (unsigned)N || (unsigned)c >= (unsigned)N) continue;
        float ev = s_r[r] + s_c[c];
        ev = (ev > 0.f) ? ev : ALPHA * ev;
        float v = expf(ev) / denom[r];
        atomicAdd(A + (size_t)r * 64 + d, v * out[(size_t)c * 128 + hcol + d]);
    }
}
__global__ __launch_bounds__(256) void f7_copy(
    const float* __restrict__ A, float* __restrict__ out, int cbase, int N)
{
    long gid = (long)blockIdx.x * 256 + threadIdx.x;
    long n = gid >> 6; int d = (int)(gid & 63);
    if (n >= N) return;
    out[(size_t)n * 128 + cbase + d] = A[(size_t)n * 64 + d];
}

extern "C" void kernel_launch(void* const* d_in, const int* in_sizes, int n_in,
                              void* d_out, int out_size, void* d_ws, size_t ws_size,
                              hipStream_t stream) {
    const float* x     = (const float*)d_in[0];
    const int*   ei    = (const int*)d_in[1];
    const float* W     = (const float*)d_in[2];
    const float* b     = (const float*)d_in[3];
    const float* fc    = (const float*)d_in[4];
    const float* bfv   = (const float*)d_in[5];
    const float* a_src = (const float*)d_in[6];
    const float* a_dst = (const float*)d_in[7];
    float* out = (float*)d_out;

    const int N = in_sizes[0] / 128;
    const int E = in_sizes[1] / 2;
    const int* row = ei;
    const int* col = ei + E;
    (void)n_in; (void)out_size;

    const int B  = (N + 31) >> 5;             // buckets (32 rows each)
    const int M  = B * 256;                   // hist elements
    const int CH = (E + 255) / 256;           // edges per p1/p2 block
    const int nbh = (M + 4095) / 4096;        // hist-scan chunks

    // --- Path P7 (radix CSR, zero global atomics, ~96 MB):
    //   Hb[N*128 u16] | A1b[N*64 u16] | WT[16384 u16] | pkA[E*8B] | pkB[E*8B]
    //   | hist[B*256] | bstart[B+1] | s_r | s_c | rp | bsum | boff
    unsigned short* Hb   = (unsigned short*)d_ws;
    unsigned short* A1b  = Hb + (size_t)N * 128;
    unsigned short* WT   = A1b + (size_t)N * 64;
    uint2*          pkA  = (uint2*)(WT + 16384);
    uint2*          pkB  = pkA + E;
    int*            hist = (int*)(pkB + E);
    int*            bst  = hist + (size_t)M;
    float*          s_rP = (float*)(bst + (B + 1));
    float*          s_cP = s_rP + 2 * (size_t)N;
    int*            rpP  = (int*)(s_cP + 2 * (size_t)N);
    int*            bsumP = rpP + (N + 1);
    int*            boffP = bsumP + 256;
    size_t          needP = (size_t)((char*)(boffP + 256) - (char*)d_ws);

    // --- Path A (colp fp32, ~67 MB): A0 | A1 | colp | s | rp | cnt | scan
    float* A0a   = (float*)d_ws;
    float* A1a   = A0a + (size_t)N * 64;
    int*   colpA = (int*)(A1a + (size_t)N * 64);
    float* s_rA  = (float*)(colpA + E);
    float* s_cA  = s_rA + 2 * (size_t)N;
    int*   rpA   = (int*)(s_cA + 2 * (size_t)N);
    int*   cntA  = rpA + (N + 1);
    int*   bsumA = cntA + N;
    int*   boffA = bsumA + 256;
    size_t needA = (size_t)((char*)(boffA + 256) - (char*)d_ws);

    const int g10 = 2 * ((N + 31) / 32);     // f10_h grid
    const int g14 = 2 * ((N + 63) / 64);     // f14_h grid (64 rows/block)
    const int eb  = (E + 255) / 256;
    const int rb  = (int)(((long)N * 64 + 255) / 256);
    const int nb  = (N + 1023) / 1024;

    if (ws_size >= needP && B <= 4096 && nbh <= 256) {
        // ================ Path P7 (radix CSR, no global atomics) ===========
        f17_p1<<<256, 256, 0, stream>>>(row, col, E, N, B, CH, hist, W, WT);
        f14_h<<<g14, 256, 0, stream>>>(x, WT, a_src, a_dst, Hb, s_rP, s_cP, N);
        f17_sc1<<<nbh, 256, 0, stream>>>(hist, bsumP, M);
        f8_scan2<<<1, 256, 0, stream>>>(bsumP, boffP, nbh);
        f17_sc3<<<nbh, 256, 0, stream>>>(hist, boffP, bst, M);
        f17_p2<<<256, 256, 0, stream>>>(row, col, E, N, B, CH, hist,
                                        s_rP, s_cP, pkA);
        f17_p3<<<B, 256, 0, stream>>>(pkA, bst, N, B, pkB, rpP);
        f12_spmm2<<<rb, 256, 0, stream>>>(rpP, pkB, (const unsigned*)Hb,
                                          b, fc, bfv, A1b, out, N);
        f16_fin2<<<rb, 256, 0, stream>>>(rpP, pkB, (const unsigned*)A1b,
                                         b, fc, bfv, out, N);
    } else if (ws_size >= needA) {
        // ======================= Path A (colp CSR) ========================
        hipMemsetAsync(cntA, 0, (size_t)N * sizeof(int), stream);
        f10_h<<<g10, 256, 0, stream>>>(x, W, a_src, a_dst, row, col, E, cntA,
                                       out, nullptr, s_rA, s_cA, N);
        f16_scan1<<<nb, 256, 0, stream>>>(cntA, bsumA, N, 1);
        f8_scan2<<<1, 256, 0, stream>>>(bsumA, boffA, nb);
        f16_scan3<<<nb, 256, 0, stream>>>(cntA, boffA, rpA, N, 1);
        f8_scatter<<<eb, 256, 0, stream>>>(row, col, E, cntA, colpA, N);
        f11_spmm2_cp<<<rb, 256, 0, stream>>>(rpA, colpA, s_rA, s_cA, out,
                                             A0a, A1a, N);
        f8_fin<<<rb, 256, 0, stream>>>(A0a, b, fc, bfv, out, N, 0);
        f9_spmm_fin<<<rb, 256, 0, stream>>>(rpA, colpA, s_rA + N, s_cA + N,
                                            A1a, 64, 0, b, fc, bfv, out, N, 1);
    } else {
        // ================= Path C (proven R7 atomic path) =================
        float* A     = (float*)d_ws;
        float* s_r   = A + (size_t)N * 64;
        float* s_c   = s_r + 2 * (size_t)N;
        float* denom = s_c + 2 * (size_t)N;
        const size_t planeB = (size_t)N * 64 * sizeof(float);
        const int sb = (int)(((((long)E + 7) / 8) * 64 + 255) / 256);
        hipMemsetAsync(denom, 0, 2 * (size_t)N * sizeof(float), stream);
        f10_h<<<g10, 256, 0, stream>>>(x, W, a_src, a_dst, row, col, E, nullptr,
                                       out, nullptr, s_r, s_c, N);
        f8_edge<<<eb, 256, 0, stream>>>(row, col, E, s_r, s_c, denom, nullptr, N);
        const float* s_r1 = s_r + N; const float* s_c1 = s_c + N; const float* den1 = denom + N;
        hipMemsetAsync(A, 0, planeB, stream);
        f7_spmm<<<sb, 256, 0, stream>>>(row, col, E, s_r, s_c, denom, out, 0, A, N);
        f8_fin<<<rb, 256, 0, stream>>>(A, b, fc, bfv, out, N, 0);
        hipMemsetAsync(A, 0, planeB, stream);
        f7_spmm<<<sb, 256, 0, stream>>>(row, col, E, s_r1, s_c1, den1, out, 64, A, N);
        f7_copy<<<rb, 256, 0, stream>>>(A, out, 64, N);
        hipMemsetAsync(A, 0, planeB, stream);
        f7_spmm<<<sb, 256, 0, stream>>>(row, col, E, s_r1, s_c1, den1, out, 64, A, N);
        f8_fin<<<rb, 256, 0, stream>>>(A, b, fc, bfv, out, N, 1);
    }
}